// Round 5
// baseline (604.728 us; speedup 1.0000x reference)
//
#include <hip/hip_runtime.h>
#include <math.h>

#define N_NODES_C 50000
#define N_EDGES_C 200000
#define FDIM 128
#define NRBF 20
#define CUT 5.0f
#define SC_BLK 196   // ceil(50000/256)
#define GBLOCKS 2048

__device__ __forceinline__ unsigned short f32_to_bf16(float f) {
    unsigned u = __float_as_uint(f);
    unsigned r = (u + 0x7FFFu + ((u >> 16) & 1u)) >> 16;   // RNE
    return (unsigned short)r;
}
__device__ __forceinline__ float bf16_to_f32(unsigned short h) {
    return __uint_as_float(((unsigned)h) << 16);
}

// ---------------------------------------------------------------------------
// Fused node MLP: phi = silu(s@W1 + b1) @ W2 + b2   (bf16 output)
// ---------------------------------------------------------------------------
__global__ __launch_bounds__(256) void mlp_kernel(
    const float* __restrict__ s, const float* __restrict__ W1,
    const float* __restrict__ b1, const float* __restrict__ W2,
    const float* __restrict__ b2, unsigned short* __restrict__ phi)
{
    __shared__ float sT[128 * 36];
    __shared__ float hT[128 * 36];
    __shared__ float wl[16 * 384];

    const int tid = threadIdx.x;
    const int nb  = blockIdx.x * 32;

#pragma unroll
    for (int j = 0; j < 4; ++j) {
        int fi   = tid + j * 256;
        int node = fi >> 5;
        int kq   = fi & 31;
        int gn   = nb + node; if (gn >= N_NODES_C) gn = N_NODES_C - 1;
        float4 val = *(const float4*)(s + (size_t)gn * FDIM + kq * 4);
        sT[(kq * 4 + 0) * 36 + node] = val.x;
        sT[(kq * 4 + 1) * 36 + node] = val.y;
        sT[(kq * 4 + 2) * 36 + node] = val.z;
        sT[(kq * 4 + 3) * 36 + node] = val.w;
    }

    const int tn = tid >> 5;
    const int tc = tid & 31;
    const int n0 = tn * 4;

    float acc[4][4];
#pragma unroll
    for (int i = 0; i < 4; ++i)
#pragma unroll
        for (int j = 0; j < 4; ++j) acc[i][j] = 0.f;

    for (int kt = 0; kt < 4; ++kt) {
        __syncthreads();
#pragma unroll
        for (int j = 0; j < 4; ++j) {
            int fi = tid + j * 256;
            int row = fi >> 5;
            int cq  = fi & 31;
            *(float4*)(wl + row * 128 + cq * 4) =
                *(const float4*)(W1 + (size_t)(kt * 32 + row) * FDIM + cq * 4);
        }
        __syncthreads();
#pragma unroll
        for (int k = 0; k < 32; ++k) {
            float4 a = *(const float4*)(sT + (kt * 32 + k) * 36 + n0);
            float4 b = *(const float4*)(wl + k * 128 + tc * 4);
            float av[4] = {a.x, a.y, a.z, a.w};
            float bv[4] = {b.x, b.y, b.z, b.w};
#pragma unroll
            for (int i = 0; i < 4; ++i)
#pragma unroll
                for (int jj = 0; jj < 4; ++jj)
                    acc[i][jj] += av[i] * bv[jj];
        }
    }

    {
        float4 bb = *(const float4*)(b1 + tc * 4);
        float bbv[4] = {bb.x, bb.y, bb.z, bb.w};
#pragma unroll
        for (int i = 0; i < 4; ++i)
#pragma unroll
            for (int jj = 0; jj < 4; ++jj) {
                float h = acc[i][jj] + bbv[jj];
                h = h / (1.f + __expf(-h));
                hT[(tc * 4 + jj) * 36 + n0 + i] = h;
            }
    }

    float acc2[4][12];
#pragma unroll
    for (int i = 0; i < 4; ++i)
#pragma unroll
        for (int j = 0; j < 12; ++j) acc2[i][j] = 0.f;

    for (int kt = 0; kt < 8; ++kt) {
        __syncthreads();
#pragma unroll
        for (int j = 0; j < 6; ++j) {
            int fi = tid + j * 256;
            int row = fi / 96;
            int cq  = fi % 96;
            *(float4*)(wl + row * 384 + cq * 4) =
                *(const float4*)(W2 + (size_t)(kt * 16 + row) * 384 + cq * 4);
        }
        __syncthreads();
#pragma unroll
        for (int k = 0; k < 16; ++k) {
            float4 a = *(const float4*)(hT + (kt * 16 + k) * 36 + n0);
            float av[4] = {a.x, a.y, a.z, a.w};
#pragma unroll
            for (int p = 0; p < 3; ++p) {
                float4 b = *(const float4*)(wl + k * 384 + p * 128 + tc * 4);
                float bv[4] = {b.x, b.y, b.z, b.w};
#pragma unroll
                for (int i = 0; i < 4; ++i)
#pragma unroll
                    for (int q = 0; q < 4; ++q)
                        acc2[i][p * 4 + q] += av[i] * bv[q];
            }
        }
    }

#pragma unroll
    for (int p = 0; p < 3; ++p) {
        float4 bb = *(const float4*)(b2 + p * 128 + tc * 4);
        float bbv[4] = {bb.x, bb.y, bb.z, bb.w};
#pragma unroll
        for (int i = 0; i < 4; ++i) {
            int gn = nb + n0 + i;
            if (gn < N_NODES_C) {
                ushort4 o;
                o.x = f32_to_bf16(acc2[i][p * 4 + 0] + bbv[0]);
                o.y = f32_to_bf16(acc2[i][p * 4 + 1] + bbv[1]);
                o.z = f32_to_bf16(acc2[i][p * 4 + 2] + bbv[2]);
                o.w = f32_to_bf16(acc2[i][p * 4 + 3] + bbv[3]);
                *(ushort4*)(phi + (size_t)gn * 384 + p * 128 + tc * 4) = o;
            }
        }
    }
}

// ---------------------------------------------------------------------------
// CSR build: histogram -> 3-kernel parallel scan -> fill
// ---------------------------------------------------------------------------
__global__ __launch_bounds__(256) void count_kernel(
    const int* __restrict__ dst, int* __restrict__ counts)
{
    int e = blockIdx.x * 256 + threadIdx.x;
    if (e < N_EDGES_C) atomicAdd(counts + dst[e], 1);
}

__global__ __launch_bounds__(256) void scan1_kernel(
    const int* __restrict__ counts, int* __restrict__ row_tmp,
    int* __restrict__ partial)
{
    __shared__ int sm[256];
    const int t = threadIdx.x;
    const int idx = blockIdx.x * 256 + t;
    int c = (idx < N_NODES_C) ? counts[idx] : 0;
    int x = c;
    sm[t] = x;
    __syncthreads();
#pragma unroll
    for (int off = 1; off < 256; off <<= 1) {
        int y = (t >= off) ? sm[t - off] : 0;
        __syncthreads();
        x += y;
        sm[t] = x;
        __syncthreads();
    }
    if (idx < N_NODES_C) row_tmp[idx] = x - c;
    if (t == 255) partial[blockIdx.x] = x;
}

__global__ __launch_bounds__(256) void scan2_kernel(
    const int* __restrict__ partial, int* __restrict__ poffs)
{
    __shared__ int sm[256];
    const int t = threadIdx.x;
    int c = (t < SC_BLK) ? partial[t] : 0;
    int x = c;
    sm[t] = x;
    __syncthreads();
#pragma unroll
    for (int off = 1; off < 256; off <<= 1) {
        int y = (t >= off) ? sm[t - off] : 0;
        __syncthreads();
        x += y;
        sm[t] = x;
        __syncthreads();
    }
    if (t < SC_BLK) poffs[t] = x - c;
}

__global__ __launch_bounds__(256) void scan3_kernel(
    const int* __restrict__ row_tmp, const int* __restrict__ poffs,
    int* __restrict__ row_ptr, int* __restrict__ row_fill)
{
    const int idx = blockIdx.x * 256 + threadIdx.x;
    if (idx < N_NODES_C) {
        int rp = row_tmp[idx] + poffs[blockIdx.x];
        row_ptr[idx]  = rp;
        row_fill[idx] = rp;
    }
    if (idx == 0) row_ptr[N_NODES_C] = N_EDGES_C;
}

// ---------------------------------------------------------------------------
// Edge precompute into dst-sorted slots (one 96B blob per edge):
//   e_meta[pos][0..3]  = (dx, dy, dz, fcut)
//   e_meta[pos][4..23] = rbf[k] * invd * fcut   (k = 0..19)
//   esrc[pos] = src
// ---------------------------------------------------------------------------
__global__ __launch_bounds__(256) void fill_kernel(
    const float* __restrict__ rel_pos, const int* __restrict__ src,
    const int* __restrict__ dst, int* __restrict__ row_fill,
    float* __restrict__ e_meta, int* __restrict__ esrc)
{
    int e = blockIdx.x * 256 + threadIdx.x;
    if (e >= N_EDGES_C) return;

    int pos = atomicAdd(row_fill + dst[e], 1);

    float x = rel_pos[3 * e + 0];
    float y = rel_pos[3 * e + 1];
    float z = rel_pos[3 * e + 2];
    float d = sqrtf(x * x + y * y + z * z);
    float invd = 1.0f / d;

    float s1 = 0.f, c1 = 0.f, fcut = 0.f, amp = 0.f;
    if (d < CUT) {
        sincosf((3.14159265358979f / CUT) * d, &s1, &c1);
        fcut = 0.5f * (c1 + 1.0f);
        amp  = invd * fcut;
    }

    float rb[NRBF];
    float sk = s1, ck = c1;
#pragma unroll
    for (int k = 0; k < NRBF; ++k) {
        rb[k] = sk * amp;
        float sn = sk * c1 + ck * s1;
        ck = ck * c1 - sk * s1;
        sk = sn;
    }

    float4* mp = (float4*)(e_meta + (size_t)pos * 24);
    float4 m0 = {x * invd, y * invd, z * invd, fcut};
    mp[0] = m0;
    mp[1] = make_float4(rb[0],  rb[1],  rb[2],  rb[3]);
    mp[2] = make_float4(rb[4],  rb[5],  rb[6],  rb[7]);
    mp[3] = make_float4(rb[8],  rb[9],  rb[10], rb[11]);
    mp[4] = make_float4(rb[12], rb[13], rb[14], rb[15]);
    mp[5] = make_float4(rb[16], rb[17], rb[18], rb[19]);
    esrc[pos] = src[e];
}

// ---------------------------------------------------------------------------
// Gather kernel: persistent blocks, contiguous node chunks, 2-deep software
// pipeline over edges (rows prefetched one iteration ahead, esrc two ahead).
// ---------------------------------------------------------------------------
#define LOADROWS(P0, P1, P2, V0, V1, V2, SI)                                   \
    {                                                                          \
        const unsigned short* ph_ = phi + (size_t)(SI) * 384;                  \
        const float*          vr_ = v   + (size_t)(SI) * 384;                  \
        P0 = bf16_to_f32(ph_[f]);                                              \
        P1 = bf16_to_f32(ph_[128 + f]);                                        \
        P2 = bf16_to_f32(ph_[256 + f]);                                        \
        V0 = vr_[f];                                                           \
        V1 = vr_[128 + f];                                                     \
        V2 = vr_[256 + f];                                                     \
    }

#define COMPUTE(IDX, P0, P1, P2, V0, V1, V2)                                   \
    {                                                                          \
        const float* mp_ = e_meta + (size_t)(IDX) * 24;                        \
        float4 m0 = *(const float4*)(mp_);                                     \
        float4 m1 = *(const float4*)(mp_ + 4);                                 \
        float4 m2 = *(const float4*)(mp_ + 8);                                 \
        float4 m3 = *(const float4*)(mp_ + 12);                                \
        float4 m4 = *(const float4*)(mp_ + 16);                                \
        float4 m5 = *(const float4*)(mp_ + 20);                                \
        float rr[NRBF] = {m1.x, m1.y, m1.z, m1.w, m2.x, m2.y, m2.z, m2.w,      \
                          m3.x, m3.y, m3.z, m3.w, m4.x, m4.y, m4.z, m4.w,      \
                          m5.x, m5.y, m5.z, m5.w};                             \
        float w0 = br0 * m0.w, w1 = br1 * m0.w, w2 = br2 * m0.w;               \
        _Pragma("unroll")                                                      \
        for (int k = 0; k < NRBF; ++k) {                                       \
            w0 += rr[k] * wr0[k];                                              \
            w1 += rr[k] * wr1[k];                                              \
            w2 += rr[k] * wr2[k];                                              \
        }                                                                      \
        float sv = w0 * (P0);                                                  \
        float ss = w1 * (P1);                                                  \
        float sr = w2 * (P2);                                                  \
        acc_s  += ss;                                                          \
        acc_v0 += (V0) * sv + m0.x * sr;                                       \
        acc_v1 += (V1) * sv + m0.y * sr;                                       \
        acc_v2 += (V2) * sv + m0.z * sr;                                       \
    }

__global__ __launch_bounds__(256, 4) void gather_kernel(
    const float* __restrict__ v, const float* __restrict__ Wr,
    const float* __restrict__ br, const int* __restrict__ row_ptr,
    const float* __restrict__ e_meta, const int* __restrict__ esrc,
    const unsigned short* __restrict__ phi,
    float* __restrict__ out_v, float* __restrict__ out_s)
{
    const int grp  = threadIdx.x >> 7;
    const int f    = threadIdx.x & 127;
    const int gid  = blockIdx.x * 2 + grp;
    const int ngrp = GBLOCKS * 2;
    const int chunk = (N_NODES_C + ngrp - 1) / ngrp;   // contiguous nodes/group

    // per-lane Wr column weights (fixed by f) -> registers, loaded once
    float wr0[NRBF], wr1[NRBF], wr2[NRBF];
#pragma unroll
    for (int k = 0; k < NRBF; ++k) {
        wr0[k] = Wr[k * 384 +       f];
        wr1[k] = Wr[k * 384 + 128 + f];
        wr2[k] = Wr[k * 384 + 256 + f];
    }
    const float br0 = br[f], br1 = br[128 + f], br2 = br[256 + f];

    const int nlo = gid * chunk;
    const int nhi = min(nlo + chunk, N_NODES_C);

    for (int n = nlo; n < nhi; ++n) {
        const int beg = row_ptr[n];
        const int cnt = row_ptr[n + 1] - beg;

        float acc_s = 0.f, acc_v0 = 0.f, acc_v1 = 0.f, acc_v2 = 0.f;

        if (cnt > 0) {
            float pA0, pA1, pA2, vA0, vA1, vA2;
            float pB0, pB1, pB2, vB0, vB1, vB2;

            int si0 = esrc[beg];
            LOADROWS(pA0, pA1, pA2, vA0, vA1, vA2, si0);
            int siN = (cnt > 1) ? esrc[beg + 1] : 0;

            int t = 0;
            while (true) {
                // set A holds rows(t); siN = src(t+1)
                if (t + 1 < cnt) LOADROWS(pB0, pB1, pB2, vB0, vB1, vB2, siN);
                int siN2 = (t + 2 < cnt) ? esrc[beg + t + 2] : 0;
                COMPUTE(beg + t, pA0, pA1, pA2, vA0, vA1, vA2);
                ++t; if (t >= cnt) break;

                // set B holds rows(t); siN2 = src(t+1)
                if (t + 1 < cnt) LOADROWS(pA0, pA1, pA2, vA0, vA1, vA2, siN2);
                siN = (t + 2 < cnt) ? esrc[beg + t + 2] : 0;
                COMPUTE(beg + t, pB0, pB1, pB2, vB0, vB1, vB2);
                ++t; if (t >= cnt) break;
            }
        }

        out_s[(size_t)n * 128 + f] = acc_s;
        out_v[(size_t)n * 384 +       f] = acc_v0;
        out_v[(size_t)n * 384 + 128 + f] = acc_v1;
        out_v[(size_t)n * 384 + 256 + f] = acc_v2;
    }
}

// ---------------------------------------------------------------------------
extern "C" void kernel_launch(void* const* d_in, const int* in_sizes, int n_in,
                              void* d_out, int out_size, void* d_ws, size_t ws_size,
                              hipStream_t stream)
{
    const float* s  = (const float*)d_in[0];
    const float* v  = (const float*)d_in[1];
    const float* rp = (const float*)d_in[2];
    const float* W1 = (const float*)d_in[3];
    const float* b1 = (const float*)d_in[4];
    const float* W2 = (const float*)d_in[5];
    const float* b2 = (const float*)d_in[6];
    const float* Wr = (const float*)d_in[7];
    const float* br = (const float*)d_in[8];
    const int* src  = (const int*)d_in[9];
    const int* dst  = (const int*)d_in[10];

    float* out   = (float*)d_out;
    float* out_v = out;                                    // 50000*3*128
    float* out_s = out + (size_t)N_NODES_C * 3 * FDIM;     // 50000*128

    // workspace layout (16B-aligned pieces first)
    char* ws = (char*)d_ws;
    unsigned short* phi = (unsigned short*)ws;    ws += (size_t)N_NODES_C * 384 * sizeof(unsigned short);
    float* e_meta = (float*)ws;                   ws += (size_t)N_EDGES_C * 24 * sizeof(float);
    int* esrc     = (int*)ws;                     ws += (size_t)N_EDGES_C * sizeof(int);
    int* counts   = (int*)ws;                     ws += (size_t)N_NODES_C * sizeof(int);
    int* row_ptr  = (int*)ws;                     ws += (size_t)(N_NODES_C + 1) * sizeof(int);
    int* row_fill = (int*)ws;                     ws += (size_t)N_NODES_C * sizeof(int);
    int* row_tmp  = (int*)ws;                     ws += (size_t)N_NODES_C * sizeof(int);
    int* partial  = (int*)ws;                     ws += (size_t)256 * sizeof(int);
    int* poffs    = (int*)ws;

    hipMemsetAsync(counts, 0, (size_t)N_NODES_C * sizeof(int), stream);

    count_kernel<<<(N_EDGES_C + 255) / 256, 256, 0, stream>>>(dst, counts);
    scan1_kernel<<<SC_BLK, 256, 0, stream>>>(counts, row_tmp, partial);
    scan2_kernel<<<1, 256, 0, stream>>>(partial, poffs);
    scan3_kernel<<<SC_BLK, 256, 0, stream>>>(row_tmp, poffs, row_ptr, row_fill);
    fill_kernel<<<(N_EDGES_C + 255) / 256, 256, 0, stream>>>(rp, src, dst, row_fill,
                                                             e_meta, esrc);
    mlp_kernel<<<(N_NODES_C + 31) / 32, 256, 0, stream>>>(s, W1, b1, W2, b2, phi);
    gather_kernel<<<GBLOCKS, 256, 0, stream>>>(v, Wr, br, row_ptr, e_meta, esrc,
                                               phi, out_v, out_s);
}

// Round 6
// 430.347 us; speedup vs baseline: 1.4052x; 1.4052x over previous
//
#include <hip/hip_runtime.h>
#include <math.h>

#define N_NODES_C 50000
#define N_EDGES_C 200000
#define FDIM 128
#define NRBF 20
#define CUT 5.0f
#define SC_BLK 196   // ceil(50000/256)
#define GBLOCKS 2048

__device__ __forceinline__ unsigned short f32_to_bf16(float f) {
    unsigned u = __float_as_uint(f);
    unsigned r = (u + 0x7FFFu + ((u >> 16) & 1u)) >> 16;   // RNE
    return (unsigned short)r;
}
__device__ __forceinline__ float bf16_to_f32(unsigned short h) {
    return __uint_as_float(((unsigned)h) << 16);
}

// ---------------------------------------------------------------------------
// Fused node MLP: phi = silu(s@W1 + b1) @ W2 + b2   (bf16 output)
// ---------------------------------------------------------------------------
__global__ __launch_bounds__(256) void mlp_kernel(
    const float* __restrict__ s, const float* __restrict__ W1,
    const float* __restrict__ b1, const float* __restrict__ W2,
    const float* __restrict__ b2, unsigned short* __restrict__ phi)
{
    __shared__ float sT[128 * 36];
    __shared__ float hT[128 * 36];
    __shared__ float wl[16 * 384];

    const int tid = threadIdx.x;
    const int nb  = blockIdx.x * 32;

#pragma unroll
    for (int j = 0; j < 4; ++j) {
        int fi   = tid + j * 256;
        int node = fi >> 5;
        int kq   = fi & 31;
        int gn   = nb + node; if (gn >= N_NODES_C) gn = N_NODES_C - 1;
        float4 val = *(const float4*)(s + (size_t)gn * FDIM + kq * 4);
        sT[(kq * 4 + 0) * 36 + node] = val.x;
        sT[(kq * 4 + 1) * 36 + node] = val.y;
        sT[(kq * 4 + 2) * 36 + node] = val.z;
        sT[(kq * 4 + 3) * 36 + node] = val.w;
    }

    const int tn = tid >> 5;
    const int tc = tid & 31;
    const int n0 = tn * 4;

    float acc[4][4];
#pragma unroll
    for (int i = 0; i < 4; ++i)
#pragma unroll
        for (int j = 0; j < 4; ++j) acc[i][j] = 0.f;

    for (int kt = 0; kt < 4; ++kt) {
        __syncthreads();
#pragma unroll
        for (int j = 0; j < 4; ++j) {
            int fi = tid + j * 256;
            int row = fi >> 5;
            int cq  = fi & 31;
            *(float4*)(wl + row * 128 + cq * 4) =
                *(const float4*)(W1 + (size_t)(kt * 32 + row) * FDIM + cq * 4);
        }
        __syncthreads();
#pragma unroll
        for (int k = 0; k < 32; ++k) {
            float4 a = *(const float4*)(sT + (kt * 32 + k) * 36 + n0);
            float4 b = *(const float4*)(wl + k * 128 + tc * 4);
            float av[4] = {a.x, a.y, a.z, a.w};
            float bv[4] = {b.x, b.y, b.z, b.w};
#pragma unroll
            for (int i = 0; i < 4; ++i)
#pragma unroll
                for (int jj = 0; jj < 4; ++jj)
                    acc[i][jj] += av[i] * bv[jj];
        }
    }

    {
        float4 bb = *(const float4*)(b1 + tc * 4);
        float bbv[4] = {bb.x, bb.y, bb.z, bb.w};
#pragma unroll
        for (int i = 0; i < 4; ++i)
#pragma unroll
            for (int jj = 0; jj < 4; ++jj) {
                float h = acc[i][jj] + bbv[jj];
                h = h / (1.f + __expf(-h));
                hT[(tc * 4 + jj) * 36 + n0 + i] = h;
            }
    }

    float acc2[4][12];
#pragma unroll
    for (int i = 0; i < 4; ++i)
#pragma unroll
        for (int j = 0; j < 12; ++j) acc2[i][j] = 0.f;

    for (int kt = 0; kt < 8; ++kt) {
        __syncthreads();
#pragma unroll
        for (int j = 0; j < 6; ++j) {
            int fi = tid + j * 256;
            int row = fi / 96;
            int cq  = fi % 96;
            *(float4*)(wl + row * 384 + cq * 4) =
                *(const float4*)(W2 + (size_t)(kt * 16 + row) * 384 + cq * 4);
        }
        __syncthreads();
#pragma unroll
        for (int k = 0; k < 16; ++k) {
            float4 a = *(const float4*)(hT + (kt * 16 + k) * 36 + n0);
            float av[4] = {a.x, a.y, a.z, a.w};
#pragma unroll
            for (int p = 0; p < 3; ++p) {
                float4 b = *(const float4*)(wl + k * 384 + p * 128 + tc * 4);
                float bv[4] = {b.x, b.y, b.z, b.w};
#pragma unroll
                for (int i = 0; i < 4; ++i)
#pragma unroll
                    for (int q = 0; q < 4; ++q)
                        acc2[i][p * 4 + q] += av[i] * bv[q];
            }
        }
    }

#pragma unroll
    for (int p = 0; p < 3; ++p) {
        float4 bb = *(const float4*)(b2 + p * 128 + tc * 4);
        float bbv[4] = {bb.x, bb.y, bb.z, bb.w};
#pragma unroll
        for (int i = 0; i < 4; ++i) {
            int gn = nb + n0 + i;
            if (gn < N_NODES_C) {
                ushort4 o;
                o.x = f32_to_bf16(acc2[i][p * 4 + 0] + bbv[0]);
                o.y = f32_to_bf16(acc2[i][p * 4 + 1] + bbv[1]);
                o.z = f32_to_bf16(acc2[i][p * 4 + 2] + bbv[2]);
                o.w = f32_to_bf16(acc2[i][p * 4 + 3] + bbv[3]);
                *(ushort4*)(phi + (size_t)gn * 384 + p * 128 + tc * 4) = o;
            }
        }
    }
}

// ---------------------------------------------------------------------------
// CSR build: histogram -> 3-kernel parallel scan -> fill
// ---------------------------------------------------------------------------
__global__ __launch_bounds__(256) void count_kernel(
    const int* __restrict__ dst, int* __restrict__ counts)
{
    int e = blockIdx.x * 256 + threadIdx.x;
    if (e < N_EDGES_C) atomicAdd(counts + dst[e], 1);
}

__global__ __launch_bounds__(256) void scan1_kernel(
    const int* __restrict__ counts, int* __restrict__ row_tmp,
    int* __restrict__ partial)
{
    __shared__ int sm[256];
    const int t = threadIdx.x;
    const int idx = blockIdx.x * 256 + t;
    int c = (idx < N_NODES_C) ? counts[idx] : 0;
    int x = c;
    sm[t] = x;
    __syncthreads();
#pragma unroll
    for (int off = 1; off < 256; off <<= 1) {
        int y = (t >= off) ? sm[t - off] : 0;
        __syncthreads();
        x += y;
        sm[t] = x;
        __syncthreads();
    }
    if (idx < N_NODES_C) row_tmp[idx] = x - c;
    if (t == 255) partial[blockIdx.x] = x;
}

__global__ __launch_bounds__(256) void scan2_kernel(
    const int* __restrict__ partial, int* __restrict__ poffs)
{
    __shared__ int sm[256];
    const int t = threadIdx.x;
    int c = (t < SC_BLK) ? partial[t] : 0;
    int x = c;
    sm[t] = x;
    __syncthreads();
#pragma unroll
    for (int off = 1; off < 256; off <<= 1) {
        int y = (t >= off) ? sm[t - off] : 0;
        __syncthreads();
        x += y;
        sm[t] = x;
        __syncthreads();
    }
    if (t < SC_BLK) poffs[t] = x - c;
}

__global__ __launch_bounds__(256) void scan3_kernel(
    const int* __restrict__ row_tmp, const int* __restrict__ poffs,
    int* __restrict__ row_ptr, int* __restrict__ row_fill)
{
    const int idx = blockIdx.x * 256 + threadIdx.x;
    if (idx < N_NODES_C) {
        int rp = row_tmp[idx] + poffs[blockIdx.x];
        row_ptr[idx]  = rp;
        row_fill[idx] = rp;
    }
    if (idx == 0) row_ptr[N_NODES_C] = N_EDGES_C;
}

// ---------------------------------------------------------------------------
// Edge precompute into dst-sorted slots (one 96B blob per edge):
//   e_meta[pos][0..3]  = (dx, dy, dz, fcut)
//   e_meta[pos][4..23] = rbf[k] * invd * fcut   (k = 0..19)
//   esrc[pos] = src
// ---------------------------------------------------------------------------
__global__ __launch_bounds__(256) void fill_kernel(
    const float* __restrict__ rel_pos, const int* __restrict__ src,
    const int* __restrict__ dst, int* __restrict__ row_fill,
    float* __restrict__ e_meta, int* __restrict__ esrc)
{
    int e = blockIdx.x * 256 + threadIdx.x;
    if (e >= N_EDGES_C) return;

    int pos = atomicAdd(row_fill + dst[e], 1);

    float x = rel_pos[3 * e + 0];
    float y = rel_pos[3 * e + 1];
    float z = rel_pos[3 * e + 2];
    float d = sqrtf(x * x + y * y + z * z);
    float invd = 1.0f / d;

    float s1 = 0.f, c1 = 0.f, fcut = 0.f, amp = 0.f;
    if (d < CUT) {
        sincosf((3.14159265358979f / CUT) * d, &s1, &c1);
        fcut = 0.5f * (c1 + 1.0f);
        amp  = invd * fcut;
    }

    float rb[NRBF];
    float sk = s1, ck = c1;
#pragma unroll
    for (int k = 0; k < NRBF; ++k) {
        rb[k] = sk * amp;
        float sn = sk * c1 + ck * s1;
        ck = ck * c1 - sk * s1;
        sk = sn;
    }

    float4* mp = (float4*)(e_meta + (size_t)pos * 24);
    float4 m0 = {x * invd, y * invd, z * invd, fcut};
    mp[0] = m0;
    mp[1] = make_float4(rb[0],  rb[1],  rb[2],  rb[3]);
    mp[2] = make_float4(rb[4],  rb[5],  rb[6],  rb[7]);
    mp[3] = make_float4(rb[8],  rb[9],  rb[10], rb[11]);
    mp[4] = make_float4(rb[12], rb[13], rb[14], rb[15]);
    mp[5] = make_float4(rb[16], rb[17], rb[18], rb[19]);
    esrc[pos] = src[e];
}

// ---------------------------------------------------------------------------
// Gather kernel: persistent blocks, contiguous node chunks, 2-deep software
// pipeline over edges (rows prefetched one iteration ahead, esrc two ahead).
// NOTE: no min-waves clause — (256,4) capped VGPR at 64 and spilled the 60
// Wr weights to scratch (+350MB HBM traffic, 2x slowdown). Round-5 lesson.
// ---------------------------------------------------------------------------
#define LOADROWS(P0, P1, P2, V0, V1, V2, SI)                                   \
    {                                                                          \
        const unsigned short* ph_ = phi + (size_t)(SI) * 384;                  \
        const float*          vr_ = v   + (size_t)(SI) * 384;                  \
        P0 = bf16_to_f32(ph_[f]);                                              \
        P1 = bf16_to_f32(ph_[128 + f]);                                        \
        P2 = bf16_to_f32(ph_[256 + f]);                                        \
        V0 = vr_[f];                                                           \
        V1 = vr_[128 + f];                                                     \
        V2 = vr_[256 + f];                                                     \
    }

#define COMPUTE(IDX, P0, P1, P2, V0, V1, V2)                                   \
    {                                                                          \
        const float* mp_ = e_meta + (size_t)(IDX) * 24;                        \
        float4 m0 = *(const float4*)(mp_);                                     \
        float4 m1 = *(const float4*)(mp_ + 4);                                 \
        float4 m2 = *(const float4*)(mp_ + 8);                                 \
        float4 m3 = *(const float4*)(mp_ + 12);                                \
        float4 m4 = *(const float4*)(mp_ + 16);                                \
        float4 m5 = *(const float4*)(mp_ + 20);                                \
        float rr[NRBF] = {m1.x, m1.y, m1.z, m1.w, m2.x, m2.y, m2.z, m2.w,      \
                          m3.x, m3.y, m3.z, m3.w, m4.x, m4.y, m4.z, m4.w,      \
                          m5.x, m5.y, m5.z, m5.w};                             \
        float w0 = br0 * m0.w, w1 = br1 * m0.w, w2 = br2 * m0.w;               \
        _Pragma("unroll")                                                      \
        for (int k = 0; k < NRBF; ++k) {                                       \
            w0 += rr[k] * wr0[k];                                              \
            w1 += rr[k] * wr1[k];                                              \
            w2 += rr[k] * wr2[k];                                              \
        }                                                                      \
        float sv = w0 * (P0);                                                  \
        float ss = w1 * (P1);                                                  \
        float sr = w2 * (P2);                                                  \
        acc_s  += ss;                                                          \
        acc_v0 += (V0) * sv + m0.x * sr;                                       \
        acc_v1 += (V1) * sv + m0.y * sr;                                       \
        acc_v2 += (V2) * sv + m0.z * sr;                                       \
    }

__global__ __launch_bounds__(256) void gather_kernel(
    const float* __restrict__ v, const float* __restrict__ Wr,
    const float* __restrict__ br, const int* __restrict__ row_ptr,
    const float* __restrict__ e_meta, const int* __restrict__ esrc,
    const unsigned short* __restrict__ phi,
    float* __restrict__ out_v, float* __restrict__ out_s)
{
    const int grp  = threadIdx.x >> 7;
    const int f    = threadIdx.x & 127;
    const int gid  = blockIdx.x * 2 + grp;
    const int ngrp = GBLOCKS * 2;
    const int chunk = (N_NODES_C + ngrp - 1) / ngrp;   // contiguous nodes/group

    // per-lane Wr column weights (fixed by f) -> registers, loaded once
    float wr0[NRBF], wr1[NRBF], wr2[NRBF];
#pragma unroll
    for (int k = 0; k < NRBF; ++k) {
        wr0[k] = Wr[k * 384 +       f];
        wr1[k] = Wr[k * 384 + 128 + f];
        wr2[k] = Wr[k * 384 + 256 + f];
    }
    const float br0 = br[f], br1 = br[128 + f], br2 = br[256 + f];

    const int nlo = gid * chunk;
    const int nhi = min(nlo + chunk, N_NODES_C);

    for (int n = nlo; n < nhi; ++n) {
        const int beg = row_ptr[n];
        const int cnt = row_ptr[n + 1] - beg;

        float acc_s = 0.f, acc_v0 = 0.f, acc_v1 = 0.f, acc_v2 = 0.f;

        if (cnt > 0) {
            float pA0, pA1, pA2, vA0, vA1, vA2;
            float pB0, pB1, pB2, vB0, vB1, vB2;

            int si0 = esrc[beg];
            LOADROWS(pA0, pA1, pA2, vA0, vA1, vA2, si0);
            int siN = (cnt > 1) ? esrc[beg + 1] : 0;

            int t = 0;
            while (true) {
                // set A holds rows(t); siN = src(t+1)
                if (t + 1 < cnt) LOADROWS(pB0, pB1, pB2, vB0, vB1, vB2, siN);
                int siN2 = (t + 2 < cnt) ? esrc[beg + t + 2] : 0;
                COMPUTE(beg + t, pA0, pA1, pA2, vA0, vA1, vA2);
                ++t; if (t >= cnt) break;

                // set B holds rows(t); siN2 = src(t+1)
                if (t + 1 < cnt) LOADROWS(pA0, pA1, pA2, vA0, vA1, vA2, siN2);
                siN = (t + 2 < cnt) ? esrc[beg + t + 2] : 0;
                COMPUTE(beg + t, pB0, pB1, pB2, vB0, vB1, vB2);
                ++t; if (t >= cnt) break;
            }
        }

        out_s[(size_t)n * 128 + f] = acc_s;
        out_v[(size_t)n * 384 +       f] = acc_v0;
        out_v[(size_t)n * 384 + 128 + f] = acc_v1;
        out_v[(size_t)n * 384 + 256 + f] = acc_v2;
    }
}

// ---------------------------------------------------------------------------
extern "C" void kernel_launch(void* const* d_in, const int* in_sizes, int n_in,
                              void* d_out, int out_size, void* d_ws, size_t ws_size,
                              hipStream_t stream)
{
    const float* s  = (const float*)d_in[0];
    const float* v  = (const float*)d_in[1];
    const float* rp = (const float*)d_in[2];
    const float* W1 = (const float*)d_in[3];
    const float* b1 = (const float*)d_in[4];
    const float* W2 = (const float*)d_in[5];
    const float* b2 = (const float*)d_in[6];
    const float* Wr = (const float*)d_in[7];
    const float* br = (const float*)d_in[8];
    const int* src  = (const int*)d_in[9];
    const int* dst  = (const int*)d_in[10];

    float* out   = (float*)d_out;
    float* out_v = out;                                    // 50000*3*128
    float* out_s = out + (size_t)N_NODES_C * 3 * FDIM;     // 50000*128

    // workspace layout (16B-aligned pieces first)
    char* ws = (char*)d_ws;
    unsigned short* phi = (unsigned short*)ws;    ws += (size_t)N_NODES_C * 384 * sizeof(unsigned short);
    float* e_meta = (float*)ws;                   ws += (size_t)N_EDGES_C * 24 * sizeof(float);
    int* esrc     = (int*)ws;                     ws += (size_t)N_EDGES_C * sizeof(int);
    int* counts   = (int*)ws;                     ws += (size_t)N_NODES_C * sizeof(int);
    int* row_ptr  = (int*)ws;                     ws += (size_t)(N_NODES_C + 1) * sizeof(int);
    int* row_fill = (int*)ws;                     ws += (size_t)N_NODES_C * sizeof(int);
    int* row_tmp  = (int*)ws;                     ws += (size_t)N_NODES_C * sizeof(int);
    int* partial  = (int*)ws;                     ws += (size_t)256 * sizeof(int);
    int* poffs    = (int*)ws;

    hipMemsetAsync(counts, 0, (size_t)N_NODES_C * sizeof(int), stream);

    count_kernel<<<(N_EDGES_C + 255) / 256, 256, 0, stream>>>(dst, counts);
    scan1_kernel<<<SC_BLK, 256, 0, stream>>>(counts, row_tmp, partial);
    scan2_kernel<<<1, 256, 0, stream>>>(partial, poffs);
    scan3_kernel<<<SC_BLK, 256, 0, stream>>>(row_tmp, poffs, row_ptr, row_fill);
    fill_kernel<<<(N_EDGES_C + 255) / 256, 256, 0, stream>>>(rp, src, dst, row_fill,
                                                             e_meta, esrc);
    mlp_kernel<<<(N_NODES_C + 31) / 32, 256, 0, stream>>>(s, W1, b1, W2, b2, phi);
    gather_kernel<<<GBLOCKS, 256, 0, stream>>>(v, Wr, br, row_ptr, e_meta, esrc,
                                               phi, out_v, out_s);
}

// Round 7
// 293.835 us; speedup vs baseline: 2.0581x; 1.4646x over previous
//
#include <hip/hip_runtime.h>
#include <math.h>

#define N_NODES_C 50000
#define N_EDGES_C 200000
#define FDIM 128
#define NRBF 20
#define CUT 5.0f
#define SC_BLK 196   // ceil(50000/256)
#define GBLOCKS 2048
#define BATCH 16     // edges staged per LDS batch in gather

typedef short  bf16x8 __attribute__((ext_vector_type(8)));
typedef float  f32x4  __attribute__((ext_vector_type(4)));

__device__ __forceinline__ unsigned short f32_to_bf16(float f) {
    unsigned u = __float_as_uint(f);
    unsigned r = (u + 0x7FFFu + ((u >> 16) & 1u)) >> 16;   // RNE
    return (unsigned short)r;
}
__device__ __forceinline__ float bf16_to_f32(unsigned short h) {
    return __uint_as_float(((unsigned)h) << 16);
}
__device__ __forceinline__ bf16x8 pack_bf16x8(float4 a, float4 b) {
    bf16x8 r;
    r[0] = (short)f32_to_bf16(a.x); r[1] = (short)f32_to_bf16(a.y);
    r[2] = (short)f32_to_bf16(a.z); r[3] = (short)f32_to_bf16(a.w);
    r[4] = (short)f32_to_bf16(b.x); r[5] = (short)f32_to_bf16(b.y);
    r[6] = (short)f32_to_bf16(b.z); r[7] = (short)f32_to_bf16(b.w);
    return r;
}

// ---------------------------------------------------------------------------
// Weight prep: W1t[n][k] = bf16(W1[k][n]) (128x128), W2t[n][k] = bf16(W2[k][n])
// (384 rows n, 128 cols k). Tiny, L2-resident afterwards.
// ---------------------------------------------------------------------------
__global__ __launch_bounds__(256) void prep_w_kernel(
    const float* __restrict__ W1, const float* __restrict__ W2,
    unsigned short* __restrict__ W1t, unsigned short* __restrict__ W2t)
{
    int i = blockIdx.x * 256 + threadIdx.x;
    if (i < 128 * 128) {
        int n = i >> 7, k = i & 127;
        W1t[i] = f32_to_bf16(W1[k * 128 + n]);
    }
    int j = i - 128 * 128;
    if (j >= 0 && j < 384 * 128) {
        int n = j >> 7, k = j & 127;
        W2t[j] = f32_to_bf16(W2[k * 384 + n]);
    }
}

// ---------------------------------------------------------------------------
// MLP stage 1 (MFMA): H = silu(S @ W1 + b1), bf16 out. 4 waves x 16 rows.
// Frag k-convention (both A and B): elem i of lane l <-> k = kt*32 + 8*(l>>4) + i
// (any consistent convention is correct; C/D layout is the HW-verified one).
// ---------------------------------------------------------------------------
__global__ __launch_bounds__(256) void mlp1_kernel(
    const float* __restrict__ s, const unsigned short* __restrict__ W1t,
    const float* __restrict__ b1, unsigned short* __restrict__ h)
{
    const int wv = threadIdx.x >> 6, lane = threadIdx.x & 63;
    const int m0 = blockIdx.x * 64 + wv * 16;
    const int lr = lane & 15, lg = lane >> 4;
    int arow = m0 + lr; if (arow >= N_NODES_C) arow = N_NODES_C - 1;

    f32x4 acc[8];
#pragma unroll
    for (int nt = 0; nt < 8; ++nt) acc[nt] = (f32x4){0.f, 0.f, 0.f, 0.f};

#pragma unroll
    for (int kt = 0; kt < 4; ++kt) {
        const int k0 = kt * 32 + lg * 8;
        const float4* ap = (const float4*)(s + (size_t)arow * 128 + k0);
        bf16x8 af = pack_bf16x8(ap[0], ap[1]);
#pragma unroll
        for (int nt = 0; nt < 8; ++nt) {
            bf16x8 bf = *(const bf16x8*)(W1t + (size_t)(nt * 16 + lr) * 128 + k0);
            acc[nt] = __builtin_amdgcn_mfma_f32_16x16x32_bf16(af, bf, acc[nt], 0, 0, 0);
        }
    }

    const int crow = m0 + lg * 4;
#pragma unroll
    for (int nt = 0; nt < 8; ++nt) {
        int col = nt * 16 + lr;
        float bb = b1[col];
#pragma unroll
        for (int r = 0; r < 4; ++r) {
            int m = crow + r;
            if (m < N_NODES_C) {
                float x = acc[nt][r] + bb;
                x = x / (1.f + __expf(-x));
                h[(size_t)m * 128 + col] = f32_to_bf16(x);
            }
        }
    }
}

// ---------------------------------------------------------------------------
// MLP stage 2 (MFMA): PHI = H @ W2 + b2, bf16 out. grid.y = 3 chunks of 128 cols.
// ---------------------------------------------------------------------------
__global__ __launch_bounds__(256) void mlp2_kernel(
    const unsigned short* __restrict__ h, const unsigned short* __restrict__ W2t,
    const float* __restrict__ b2, unsigned short* __restrict__ phi)
{
    const int wv = threadIdx.x >> 6, lane = threadIdx.x & 63;
    const int m0 = blockIdx.x * 64 + wv * 16;
    const int nbase = blockIdx.y * 128;
    const int lr = lane & 15, lg = lane >> 4;
    int arow = m0 + lr; if (arow >= N_NODES_C) arow = N_NODES_C - 1;

    f32x4 acc[8];
#pragma unroll
    for (int nt = 0; nt < 8; ++nt) acc[nt] = (f32x4){0.f, 0.f, 0.f, 0.f};

#pragma unroll
    for (int kt = 0; kt < 4; ++kt) {
        const int k0 = kt * 32 + lg * 8;
        bf16x8 af = *(const bf16x8*)(h + (size_t)arow * 128 + k0);
#pragma unroll
        for (int nt = 0; nt < 8; ++nt) {
            bf16x8 bf = *(const bf16x8*)(W2t + (size_t)(nbase + nt * 16 + lr) * 128 + k0);
            acc[nt] = __builtin_amdgcn_mfma_f32_16x16x32_bf16(af, bf, acc[nt], 0, 0, 0);
        }
    }

    const int crow = m0 + lg * 4;
#pragma unroll
    for (int nt = 0; nt < 8; ++nt) {
        int col = nt * 16 + lr;
        float bb = b2[nbase + col];
#pragma unroll
        for (int r = 0; r < 4; ++r) {
            int m = crow + r;
            if (m < N_NODES_C)
                phi[(size_t)m * 384 + nbase + col] = f32_to_bf16(acc[nt][r] + bb);
        }
    }
}

// ---------------------------------------------------------------------------
// CSR build: histogram -> 3-kernel parallel scan -> fill
// ---------------------------------------------------------------------------
__global__ __launch_bounds__(256) void count_kernel(
    const int* __restrict__ dst, int* __restrict__ counts)
{
    int e = blockIdx.x * 256 + threadIdx.x;
    if (e < N_EDGES_C) atomicAdd(counts + dst[e], 1);
}

__global__ __launch_bounds__(256) void scan1_kernel(
    const int* __restrict__ counts, int* __restrict__ row_tmp,
    int* __restrict__ partial)
{
    __shared__ int sm[256];
    const int t = threadIdx.x;
    const int idx = blockIdx.x * 256 + t;
    int c = (idx < N_NODES_C) ? counts[idx] : 0;
    int x = c;
    sm[t] = x;
    __syncthreads();
#pragma unroll
    for (int off = 1; off < 256; off <<= 1) {
        int y = (t >= off) ? sm[t - off] : 0;
        __syncthreads();
        x += y;
        sm[t] = x;
        __syncthreads();
    }
    if (idx < N_NODES_C) row_tmp[idx] = x - c;
    if (t == 255) partial[blockIdx.x] = x;
}

__global__ __launch_bounds__(256) void scan2_kernel(
    const int* __restrict__ partial, int* __restrict__ poffs)
{
    __shared__ int sm[256];
    const int t = threadIdx.x;
    int c = (t < SC_BLK) ? partial[t] : 0;
    int x = c;
    sm[t] = x;
    __syncthreads();
#pragma unroll
    for (int off = 1; off < 256; off <<= 1) {
        int y = (t >= off) ? sm[t - off] : 0;
        __syncthreads();
        x += y;
        sm[t] = x;
        __syncthreads();
    }
    if (t < SC_BLK) poffs[t] = x - c;
}

__global__ __launch_bounds__(256) void scan3_kernel(
    const int* __restrict__ row_tmp, const int* __restrict__ poffs,
    int* __restrict__ row_ptr, int* __restrict__ row_fill)
{
    const int idx = blockIdx.x * 256 + threadIdx.x;
    if (idx < N_NODES_C) {
        int rp = row_tmp[idx] + poffs[blockIdx.x];
        row_ptr[idx]  = rp;
        row_fill[idx] = rp;
    }
    if (idx == 0) row_ptr[N_NODES_C] = N_EDGES_C;
}

// ---------------------------------------------------------------------------
// Edge precompute into dst-sorted slots; 128B (32-float) blob per edge:
//   [0..2]=dir, [3]=fcut, [4..23]=rbf[k]*invd*fcut, [24]=bitcast(src), rest pad
// ---------------------------------------------------------------------------
__global__ __launch_bounds__(256) void fill_kernel(
    const float* __restrict__ rel_pos, const int* __restrict__ src,
    const int* __restrict__ dst, int* __restrict__ row_fill,
    float* __restrict__ e_meta)
{
    int e = blockIdx.x * 256 + threadIdx.x;
    if (e >= N_EDGES_C) return;

    int pos = atomicAdd(row_fill + dst[e], 1);

    float x = rel_pos[3 * e + 0];
    float y = rel_pos[3 * e + 1];
    float z = rel_pos[3 * e + 2];
    float d = sqrtf(x * x + y * y + z * z);
    float invd = 1.0f / d;

    float s1 = 0.f, c1 = 0.f, fcut = 0.f, amp = 0.f;
    if (d < CUT) {
        sincosf((3.14159265358979f / CUT) * d, &s1, &c1);
        fcut = 0.5f * (c1 + 1.0f);
        amp  = invd * fcut;
    }

    float rb[NRBF];
    float sk = s1, ck = c1;
#pragma unroll
    for (int k = 0; k < NRBF; ++k) {
        rb[k] = sk * amp;
        float sn = sk * c1 + ck * s1;
        ck = ck * c1 - sk * s1;
        sk = sn;
    }

    float4* mp = (float4*)(e_meta + (size_t)pos * 32);
    mp[0] = make_float4(x * invd, y * invd, z * invd, fcut);
    mp[1] = make_float4(rb[0],  rb[1],  rb[2],  rb[3]);
    mp[2] = make_float4(rb[4],  rb[5],  rb[6],  rb[7]);
    mp[3] = make_float4(rb[8],  rb[9],  rb[10], rb[11]);
    mp[4] = make_float4(rb[12], rb[13], rb[14], rb[15]);
    mp[5] = make_float4(rb[16], rb[17], rb[18], rb[19]);
    mp[6] = make_float4(__int_as_float(src[e]), 0.f, 0.f, 0.f);
}

// ---------------------------------------------------------------------------
// Gather: 1 group (128 threads, 2 waves) per block; contiguous node chunk ->
// contiguous dst-sorted edge range. Meta batch-staged through LDS (issue
// global->reg at batch start, LDS-write + 1 barrier at batch end, T14 style);
// per-edge meta reads are same-address LDS broadcasts. Row gathers ping-pong
// prefetched 1 edge ahead; node boundaries are uniform branches that never
// restart the pipeline.
// NOTE: no min-waves launch_bounds clause — (256,4) capped VGPR at 64 and
// spilled the 60 Wr weights to scratch (round-5 lesson).
// ---------------------------------------------------------------------------
#define LOADROWS(P0, P1, P2, V0, V1, V2, SI)                                   \
    {                                                                          \
        const unsigned short* ph_ = phi + (size_t)(SI) * 384;                  \
        const float*          vr_ = v   + (size_t)(SI) * 384;                  \
        P0 = bf16_to_f32(ph_[f]);                                              \
        P1 = bf16_to_f32(ph_[128 + f]);                                       \
        P2 = bf16_to_f32(ph_[256 + f]);                                       \
        V0 = vr_[f];                                                           \
        V1 = vr_[128 + f];                                                    \
        V2 = vr_[256 + f];                                                    \
    }

#define COMPUTE(MP, P0, P1, P2, V0, V1, V2)                                    \
    {                                                                          \
        const float* mp_ = (MP);                                               \
        float4 m0 = *(const float4*)(mp_);                                     \
        float4 m1 = *(const float4*)(mp_ + 4);                                 \
        float4 m2 = *(const float4*)(mp_ + 8);                                 \
        float4 m3 = *(const float4*)(mp_ + 12);                                \
        float4 m4 = *(const float4*)(mp_ + 16);                                \
        float4 m5 = *(const float4*)(mp_ + 20);                                \
        float rr[NRBF] = {m1.x, m1.y, m1.z, m1.w, m2.x, m2.y, m2.z, m2.w,      \
                          m3.x, m3.y, m3.z, m3.w, m4.x, m4.y, m4.z, m4.w,      \
                          m5.x, m5.y, m5.z, m5.w};                             \
        float w0 = br0 * m0.w, w1 = br1 * m0.w, w2 = br2 * m0.w;               \
        _Pragma("unroll")                                                      \
        for (int k = 0; k < NRBF; ++k) {                                       \
            w0 += rr[k] * wr0[k];                                              \
            w1 += rr[k] * wr1[k];                                              \
            w2 += rr[k] * wr2[k];                                              \
        }                                                                      \
        float sv = w0 * (P0);                                                  \
        float ss = w1 * (P1);                                                  \
        float sr = w2 * (P2);                                                  \
        acc_s  += ss;                                                          \
        acc_v0 += (V0) * sv + m0.x * sr;                                       \
        acc_v1 += (V1) * sv + m0.y * sr;                                       \
        acc_v2 += (V2) * sv + m0.z * sr;                                       \
    }

#define STORE_NODE(N_, AS, A0, A1, A2)                                         \
    {                                                                          \
        out_s[(size_t)(N_) * 128 + f] = AS;                                    \
        out_v[(size_t)(N_) * 384 +       f] = A0;                              \
        out_v[(size_t)(N_) * 384 + 128 + f] = A1;                              \
        out_v[(size_t)(N_) * 384 + 256 + f] = A2;                              \
    }

#define BOUNDARY(GE)                                                           \
    if ((GE) + 1 == end_cur) {                                                 \
        STORE_NODE(cur, acc_s, acc_v0, acc_v1, acc_v2);                        \
        acc_s = acc_v0 = acc_v1 = acc_v2 = 0.f;                                \
        ++cur;                                                                 \
        while (cur < nhi) {                                                    \
            int ne_ = row_ptr[cur + 1];                                        \
            if (ne_ != (GE) + 1) { end_cur = ne_; break; }                     \
            STORE_NODE(cur, 0.f, 0.f, 0.f, 0.f);                               \
            ++cur;                                                             \
        }                                                                      \
    }

__global__ __launch_bounds__(128) void gather_kernel(
    const float* __restrict__ v, const float* __restrict__ Wr,
    const float* __restrict__ br, const int* __restrict__ row_ptr,
    const float* __restrict__ e_meta, const unsigned short* __restrict__ phi,
    float* __restrict__ out_v, float* __restrict__ out_s)
{
    __shared__ float meta_lds[2][BATCH * 32];

    const int f = threadIdx.x;               // 0..127 feature lane
    const int gid = blockIdx.x;
    const int chunk = (N_NODES_C + GBLOCKS - 1) / GBLOCKS;
    const int nlo = gid * chunk;
    if (nlo >= N_NODES_C) return;
    const int nhi = min(nlo + chunk, N_NODES_C);

    // per-lane Wr column weights -> registers (fixed by f), once per block
    float wr0[NRBF], wr1[NRBF], wr2[NRBF];
#pragma unroll
    for (int k = 0; k < NRBF; ++k) {
        wr0[k] = Wr[k * 384 +       f];
        wr1[k] = Wr[k * 384 + 128 + f];
        wr2[k] = Wr[k * 384 + 256 + f];
    }
    const float br0 = br[f], br1 = br[128 + f], br2 = br[256 + f];

    const int gbeg = row_ptr[nlo];
    const int gend = row_ptr[nhi];
    const int nedge = gend - gbeg;

    float acc_s = 0.f, acc_v0 = 0.f, acc_v1 = 0.f, acc_v2 = 0.f;

    // leading empty nodes
    int cur = nlo;
    while (cur < nhi && row_ptr[cur + 1] == gbeg) {
        STORE_NODE(cur, 0.f, 0.f, 0.f, 0.f);
        ++cur;
    }
    int end_cur = (cur < nhi) ? row_ptr[cur + 1] : gbeg;

    // stage batch 0
    if (nedge > 0) {
        float4 st0 = ((const float4*)(e_meta + (size_t)gbeg * 32))[threadIdx.x];
        ((float4*)meta_lds[0])[threadIdx.x] = st0;
    }
    __syncthreads();

    const int total_batches = (nedge + BATCH - 1) / BATCH;
    for (int b = 0; b < total_batches; ++b) {
        const int bstart = b * BATCH;
        const int bcount = min(BATCH, nedge - bstart);
        const bool have_next = (b + 1 < total_batches);

        float4 st;
        if (have_next)
            st = ((const float4*)(e_meta + (size_t)(gbeg + bstart + BATCH) * 32))[threadIdx.x];

        const float* M = meta_lds[b & 1];

        float pA0, pA1, pA2, vA0, vA1, vA2;
        float pB0, pB1, pB2, vB0, vB1, vB2;
        {
            int si = __float_as_int(M[24]);
            LOADROWS(pA0, pA1, pA2, vA0, vA1, vA2, si);
        }

        int t = 0;
        while (t < bcount) {
            if (t + 1 < bcount) {
                int si = __float_as_int(M[(t + 1) * 32 + 24]);
                LOADROWS(pB0, pB1, pB2, vB0, vB1, vB2, si);
            }
            COMPUTE(M + t * 32, pA0, pA1, pA2, vA0, vA1, vA2);
            BOUNDARY(gbeg + bstart + t);
            ++t; if (t >= bcount) break;

            if (t + 1 < bcount) {
                int si = __float_as_int(M[(t + 1) * 32 + 24]);
                LOADROWS(pA0, pA1, pA2, vA0, vA1, vA2, si);
            }
            COMPUTE(M + t * 32, pB0, pB1, pB2, vB0, vB1, vB2);
            BOUNDARY(gbeg + bstart + t);
            ++t;
        }

        if (have_next) ((float4*)meta_lds[(b + 1) & 1])[threadIdx.x] = st;
        __syncthreads();
    }
}

// ---------------------------------------------------------------------------
extern "C" void kernel_launch(void* const* d_in, const int* in_sizes, int n_in,
                              void* d_out, int out_size, void* d_ws, size_t ws_size,
                              hipStream_t stream)
{
    const float* s  = (const float*)d_in[0];
    const float* v  = (const float*)d_in[1];
    const float* rp = (const float*)d_in[2];
    const float* W1 = (const float*)d_in[3];
    const float* b1 = (const float*)d_in[4];
    const float* W2 = (const float*)d_in[5];
    const float* b2 = (const float*)d_in[6];
    const float* Wr = (const float*)d_in[7];
    const float* br = (const float*)d_in[8];
    const int* src  = (const int*)d_in[9];
    const int* dst  = (const int*)d_in[10];

    float* out   = (float*)d_out;
    float* out_v = out;                                    // 50000*3*128
    float* out_s = out + (size_t)N_NODES_C * 3 * FDIM;     // 50000*128

    // workspace layout (16B-aligned pieces first)
    char* ws = (char*)d_ws;
    unsigned short* phi = (unsigned short*)ws;  ws += (size_t)N_NODES_C * 384 * sizeof(unsigned short);
    unsigned short* h   = (unsigned short*)ws;  ws += (size_t)N_NODES_C * 128 * sizeof(unsigned short);
    float* e_meta = (float*)ws;                 ws += ((size_t)N_EDGES_C * 32 + 512) * sizeof(float);
    unsigned short* W1t = (unsigned short*)ws;  ws += (size_t)128 * 128 * sizeof(unsigned short);
    unsigned short* W2t = (unsigned short*)ws;  ws += (size_t)384 * 128 * sizeof(unsigned short);
    int* counts   = (int*)ws;                   ws += (size_t)N_NODES_C * sizeof(int);
    int* row_ptr  = (int*)ws;                   ws += (size_t)(N_NODES_C + 4) * sizeof(int);
    int* row_fill = (int*)ws;                   ws += (size_t)N_NODES_C * sizeof(int);
    int* row_tmp  = (int*)ws;                   ws += (size_t)N_NODES_C * sizeof(int);
    int* partial  = (int*)ws;                   ws += (size_t)256 * sizeof(int);
    int* poffs    = (int*)ws;

    hipMemsetAsync(counts, 0, (size_t)N_NODES_C * sizeof(int), stream);

    count_kernel<<<(N_EDGES_C + 255) / 256, 256, 0, stream>>>(dst, counts);
    scan1_kernel<<<SC_BLK, 256, 0, stream>>>(counts, row_tmp, partial);
    scan2_kernel<<<1, 256, 0, stream>>>(partial, poffs);
    scan3_kernel<<<SC_BLK, 256, 0, stream>>>(row_tmp, poffs, row_ptr, row_fill);
    fill_kernel<<<(N_EDGES_C + 255) / 256, 256, 0, stream>>>(rp, src, dst, row_fill, e_meta);

    prep_w_kernel<<<256, 256, 0, stream>>>(W1, W2, W1t, W2t);
    mlp1_kernel<<<(N_NODES_C + 63) / 64, 256, 0, stream>>>(s, W1t, b1, h);
    mlp2_kernel<<<dim3((N_NODES_C + 63) / 64, 3), 256, 0, stream>>>(h, W2t, b2, phi);

    gather_kernel<<<GBLOCKS, 128, 0, stream>>>(v, Wr, br, row_ptr, e_meta, phi,
                                               out_v, out_s);
}

// Round 8
// 287.792 us; speedup vs baseline: 2.1013x; 1.0210x over previous
//
#include <hip/hip_runtime.h>
#include <math.h>

#define N_NODES_C 50000
#define N_EDGES_C 200000
#define FDIM 128
#define NRBF 20
#define CUT 5.0f
#define SC_BLK 196   // ceil(50000/256)
#define GBLOCKS 4096
#define BATCH 16     // edges staged per LDS batch in gather

typedef short  bf16x8 __attribute__((ext_vector_type(8)));
typedef float  f32x4  __attribute__((ext_vector_type(4)));

__device__ __forceinline__ unsigned short f32_to_bf16(float f) {
    unsigned u = __float_as_uint(f);
    unsigned r = (u + 0x7FFFu + ((u >> 16) & 1u)) >> 16;   // RNE
    return (unsigned short)r;
}
__device__ __forceinline__ float bf16_to_f32(unsigned short h) {
    return __uint_as_float(((unsigned)h) << 16);
}
__device__ __forceinline__ bf16x8 pack_bf16x8(float4 a, float4 b) {
    bf16x8 r;
    r[0] = (short)f32_to_bf16(a.x); r[1] = (short)f32_to_bf16(a.y);
    r[2] = (short)f32_to_bf16(a.z); r[3] = (short)f32_to_bf16(a.w);
    r[4] = (short)f32_to_bf16(b.x); r[5] = (short)f32_to_bf16(b.y);
    r[6] = (short)f32_to_bf16(b.z); r[7] = (short)f32_to_bf16(b.w);
    return r;
}

// ---------------------------------------------------------------------------
// Weight prep: W1t[n][k] = bf16(W1[k][n]) (128x128), W2t[n][k] = bf16(W2[k][n])
// ---------------------------------------------------------------------------
__global__ __launch_bounds__(256) void prep_w_kernel(
    const float* __restrict__ W1, const float* __restrict__ W2,
    unsigned short* __restrict__ W1t, unsigned short* __restrict__ W2t)
{
    int i = blockIdx.x * 256 + threadIdx.x;
    if (i < 128 * 128) {
        int n = i >> 7, k = i & 127;
        W1t[i] = f32_to_bf16(W1[k * 128 + n]);
    }
    int j = i - 128 * 128;
    if (j >= 0 && j < 384 * 128) {
        int n = j >> 7, k = j & 127;
        W2t[j] = f32_to_bf16(W2[k * 384 + n]);
    }
}

// ---------------------------------------------------------------------------
// v -> bf16 copy (grid-stride, float4 in / ushort4 out)
// ---------------------------------------------------------------------------
__global__ __launch_bounds__(256) void vprep_kernel(
    const float* __restrict__ v, unsigned short* __restrict__ vt)
{
    const size_t total = (size_t)N_NODES_C * 96;   // float4 count (384/4)
    for (size_t i = (size_t)blockIdx.x * 256 + threadIdx.x; i < total;
         i += (size_t)gridDim.x * 256) {
        float4 a = ((const float4*)v)[i];
        ushort4 o;
        o.x = f32_to_bf16(a.x); o.y = f32_to_bf16(a.y);
        o.z = f32_to_bf16(a.z); o.w = f32_to_bf16(a.w);
        ((ushort4*)vt)[i] = o;
    }
}

// ---------------------------------------------------------------------------
// MLP stage 1 (MFMA): H = silu(S @ W1 + b1), bf16 out. 4 waves x 16 rows.
// ---------------------------------------------------------------------------
__global__ __launch_bounds__(256) void mlp1_kernel(
    const float* __restrict__ s, const unsigned short* __restrict__ W1t,
    const float* __restrict__ b1, unsigned short* __restrict__ h)
{
    const int wv = threadIdx.x >> 6, lane = threadIdx.x & 63;
    const int m0 = blockIdx.x * 64 + wv * 16;
    const int lr = lane & 15, lg = lane >> 4;
    int arow = m0 + lr; if (arow >= N_NODES_C) arow = N_NODES_C - 1;

    f32x4 acc[8];
#pragma unroll
    for (int nt = 0; nt < 8; ++nt) acc[nt] = (f32x4){0.f, 0.f, 0.f, 0.f};

#pragma unroll
    for (int kt = 0; kt < 4; ++kt) {
        const int k0 = kt * 32 + lg * 8;
        const float4* ap = (const float4*)(s + (size_t)arow * 128 + k0);
        bf16x8 af = pack_bf16x8(ap[0], ap[1]);
#pragma unroll
        for (int nt = 0; nt < 8; ++nt) {
            bf16x8 bf = *(const bf16x8*)(W1t + (size_t)(nt * 16 + lr) * 128 + k0);
            acc[nt] = __builtin_amdgcn_mfma_f32_16x16x32_bf16(af, bf, acc[nt], 0, 0, 0);
        }
    }

    const int crow = m0 + lg * 4;
#pragma unroll
    for (int nt = 0; nt < 8; ++nt) {
        int col = nt * 16 + lr;
        float bb = b1[col];
#pragma unroll
        for (int r = 0; r < 4; ++r) {
            int m = crow + r;
            if (m < N_NODES_C) {
                float x = acc[nt][r] + bb;
                x = x / (1.f + __expf(-x));
                h[(size_t)m * 128 + col] = f32_to_bf16(x);
            }
        }
    }
}

// ---------------------------------------------------------------------------
// MLP stage 2 (MFMA): PHI = H @ W2 + b2, all 3 column chunks in one kernel
// (A-frags loaded once, reused 3x).
// ---------------------------------------------------------------------------
__global__ __launch_bounds__(256) void mlp2_kernel(
    const unsigned short* __restrict__ h, const unsigned short* __restrict__ W2t,
    const float* __restrict__ b2, unsigned short* __restrict__ phi)
{
    const int wv = threadIdx.x >> 6, lane = threadIdx.x & 63;
    const int m0 = blockIdx.x * 64 + wv * 16;
    const int lr = lane & 15, lg = lane >> 4;
    int arow = m0 + lr; if (arow >= N_NODES_C) arow = N_NODES_C - 1;

    bf16x8 af[4];
#pragma unroll
    for (int kt = 0; kt < 4; ++kt)
        af[kt] = *(const bf16x8*)(h + (size_t)arow * 128 + kt * 32 + lg * 8);

    const int crow = m0 + lg * 4;

#pragma unroll
    for (int c = 0; c < 3; ++c) {
        const int nbase = c * 128;
        f32x4 acc[8];
#pragma unroll
        for (int nt = 0; nt < 8; ++nt) acc[nt] = (f32x4){0.f, 0.f, 0.f, 0.f};

#pragma unroll
        for (int kt = 0; kt < 4; ++kt) {
            const int k0 = kt * 32 + lg * 8;
#pragma unroll
            for (int nt = 0; nt < 8; ++nt) {
                bf16x8 bf = *(const bf16x8*)(W2t + (size_t)(nbase + nt * 16 + lr) * 128 + k0);
                acc[nt] = __builtin_amdgcn_mfma_f32_16x16x32_bf16(af[kt], bf, acc[nt], 0, 0, 0);
            }
        }

#pragma unroll
        for (int nt = 0; nt < 8; ++nt) {
            int col = nt * 16 + lr;
            float bb = b2[nbase + col];
#pragma unroll
            for (int r = 0; r < 4; ++r) {
                int m = crow + r;
                if (m < N_NODES_C)
                    phi[(size_t)m * 384 + nbase + col] = f32_to_bf16(acc[nt][r] + bb);
            }
        }
    }
}

// ---------------------------------------------------------------------------
// CSR build: histogram -> 3-kernel parallel scan -> fill
// ---------------------------------------------------------------------------
__global__ __launch_bounds__(256) void count_kernel(
    const int* __restrict__ dst, int* __restrict__ counts)
{
    int e = blockIdx.x * 256 + threadIdx.x;
    if (e < N_EDGES_C) atomicAdd(counts + dst[e], 1);
}

__global__ __launch_bounds__(256) void scan1_kernel(
    const int* __restrict__ counts, int* __restrict__ row_tmp,
    int* __restrict__ partial)
{
    __shared__ int sm[256];
    const int t = threadIdx.x;
    const int idx = blockIdx.x * 256 + t;
    int c = (idx < N_NODES_C) ? counts[idx] : 0;
    int x = c;
    sm[t] = x;
    __syncthreads();
#pragma unroll
    for (int off = 1; off < 256; off <<= 1) {
        int y = (t >= off) ? sm[t - off] : 0;
        __syncthreads();
        x += y;
        sm[t] = x;
        __syncthreads();
    }
    if (idx < N_NODES_C) row_tmp[idx] = x - c;
    if (t == 255) partial[blockIdx.x] = x;
}

__global__ __launch_bounds__(256) void scan2_kernel(
    const int* __restrict__ partial, int* __restrict__ poffs)
{
    __shared__ int sm[256];
    const int t = threadIdx.x;
    int c = (t < SC_BLK) ? partial[t] : 0;
    int x = c;
    sm[t] = x;
    __syncthreads();
#pragma unroll
    for (int off = 1; off < 256; off <<= 1) {
        int y = (t >= off) ? sm[t - off] : 0;
        __syncthreads();
        x += y;
        sm[t] = x;
        __syncthreads();
    }
    if (t < SC_BLK) poffs[t] = x - c;
}

__global__ __launch_bounds__(256) void scan3_kernel(
    const int* __restrict__ row_tmp, const int* __restrict__ poffs,
    int* __restrict__ row_ptr, int* __restrict__ row_fill)
{
    const int idx = blockIdx.x * 256 + threadIdx.x;
    if (idx < N_NODES_C) {
        int rp = row_tmp[idx] + poffs[blockIdx.x];
        row_ptr[idx]  = rp;
        row_fill[idx] = rp;
    }
    if (idx == 0) row_ptr[N_NODES_C] = N_EDGES_C;
}

// ---------------------------------------------------------------------------
// Edge precompute into dst-sorted slots; 128B (32-float) blob per edge:
//   [0..2]=dir, [3]=fcut, [4..23]=rbf[k]*invd*fcut, [24]=bitcast(src), rest pad
// ---------------------------------------------------------------------------
__global__ __launch_bounds__(256) void fill_kernel(
    const float* __restrict__ rel_pos, const int* __restrict__ src,
    const int* __restrict__ dst, int* __restrict__ row_fill,
    float* __restrict__ e_meta)
{
    int e = blockIdx.x * 256 + threadIdx.x;
    if (e >= N_EDGES_C) return;

    int pos = atomicAdd(row_fill + dst[e], 1);

    float x = rel_pos[3 * e + 0];
    float y = rel_pos[3 * e + 1];
    float z = rel_pos[3 * e + 2];
    float d = sqrtf(x * x + y * y + z * z);
    float invd = 1.0f / d;

    float s1 = 0.f, c1 = 0.f, fcut = 0.f, amp = 0.f;
    if (d < CUT) {
        sincosf((3.14159265358979f / CUT) * d, &s1, &c1);
        fcut = 0.5f * (c1 + 1.0f);
        amp  = invd * fcut;
    }

    float rb[NRBF];
    float sk = s1, ck = c1;
#pragma unroll
    for (int k = 0; k < NRBF; ++k) {
        rb[k] = sk * amp;
        float sn = sk * c1 + ck * s1;
        ck = ck * c1 - sk * s1;
        sk = sn;
    }

    float4* mp = (float4*)(e_meta + (size_t)pos * 32);
    mp[0] = make_float4(x * invd, y * invd, z * invd, fcut);
    mp[1] = make_float4(rb[0],  rb[1],  rb[2],  rb[3]);
    mp[2] = make_float4(rb[4],  rb[5],  rb[6],  rb[7]);
    mp[3] = make_float4(rb[8],  rb[9],  rb[10], rb[11]);
    mp[4] = make_float4(rb[12], rb[13], rb[14], rb[15]);
    mp[5] = make_float4(rb[16], rb[17], rb[18], rb[19]);
    mp[6] = make_float4(__int_as_float(src[e]), 0.f, 0.f, 0.f);
}

// ---------------------------------------------------------------------------
// Gather: 1 group (128 threads, 2 waves) per block; contiguous node chunk ->
// contiguous dst-sorted edge range. Meta batch-staged through LDS; row gathers
// ping-pong prefetched 1 edge ahead; node boundaries never restart the
// pipeline. Template BF16V: v read as bf16 (vt) or f32 fallback.
// NOTE: no min-waves launch_bounds clause (round-5 spill lesson).
// ---------------------------------------------------------------------------
#define LOADROWS(P0, P1, P2, V0, V1, V2, SI)                                   \
    {                                                                          \
        const unsigned short* ph_ = phi + (size_t)(SI) * 384;                  \
        P0 = bf16_to_f32(ph_[f]);                                              \
        P1 = bf16_to_f32(ph_[128 + f]);                                       \
        P2 = bf16_to_f32(ph_[256 + f]);                                       \
        if constexpr (BF16V) {                                                 \
            const unsigned short* vr_ = vt + (size_t)(SI) * 384;               \
            V0 = bf16_to_f32(vr_[f]);                                          \
            V1 = bf16_to_f32(vr_[128 + f]);                                   \
            V2 = bf16_to_f32(vr_[256 + f]);                                   \
        } else {                                                               \
            const float* vr_ = v + (size_t)(SI) * 384;                         \
            V0 = vr_[f];                                                       \
            V1 = vr_[128 + f];                                                \
            V2 = vr_[256 + f];                                                \
        }                                                                      \
    }

#define COMPUTE(MP, P0, P1, P2, V0, V1, V2)                                    \
    {                                                                          \
        const float* mp_ = (MP);                                               \
        float4 m0 = *(const float4*)(mp_);                                     \
        float4 m1 = *(const float4*)(mp_ + 4);                                 \
        float4 m2 = *(const float4*)(mp_ + 8);                                 \
        float4 m3 = *(const float4*)(mp_ + 12);                                \
        float4 m4 = *(const float4*)(mp_ + 16);                                \
        float4 m5 = *(const float4*)(mp_ + 20);                                \
        float rr[NRBF] = {m1.x, m1.y, m1.z, m1.w, m2.x, m2.y, m2.z, m2.w,      \
                          m3.x, m3.y, m3.z, m3.w, m4.x, m4.y, m4.z, m4.w,      \
                          m5.x, m5.y, m5.z, m5.w};                             \
        float w0 = br0 * m0.w, w1 = br1 * m0.w, w2 = br2 * m0.w;               \
        _Pragma("unroll")                                                      \
        for (int k = 0; k < NRBF; ++k) {                                       \
            w0 += rr[k] * wr0[k];                                              \
            w1 += rr[k] * wr1[k];                                              \
            w2 += rr[k] * wr2[k];                                              \
        }                                                                      \
        float sv = w0 * (P0);                                                  \
        float ss = w1 * (P1);                                                  \
        float sr = w2 * (P2);                                                  \
        acc_s  += ss;                                                          \
        acc_v0 += (V0) * sv + m0.x * sr;                                       \
        acc_v1 += (V1) * sv + m0.y * sr;                                       \
        acc_v2 += (V2) * sv + m0.z * sr;                                       \
    }

#define STORE_NODE(N_, AS, A0, A1, A2)                                         \
    {                                                                          \
        out_s[(size_t)(N_) * 128 + f] = AS;                                    \
        out_v[(size_t)(N_) * 384 +       f] = A0;                              \
        out_v[(size_t)(N_) * 384 + 128 + f] = A1;                              \
        out_v[(size_t)(N_) * 384 + 256 + f] = A2;                              \
    }

#define BOUNDARY(GE)                                                           \
    if ((GE) + 1 == end_cur) {                                                 \
        STORE_NODE(cur, acc_s, acc_v0, acc_v1, acc_v2);                        \
        acc_s = acc_v0 = acc_v1 = acc_v2 = 0.f;                                \
        ++cur;                                                                 \
        while (cur < nhi) {                                                    \
            int ne_ = row_ptr[cur + 1];                                        \
            if (ne_ != (GE) + 1) { end_cur = ne_; break; }                     \
            STORE_NODE(cur, 0.f, 0.f, 0.f, 0.f);                               \
            ++cur;                                                             \
        }                                                                      \
    }

template <bool BF16V>
__global__ __launch_bounds__(128) void gather_kernel(
    const float* __restrict__ v, const unsigned short* __restrict__ vt,
    const float* __restrict__ Wr, const float* __restrict__ br,
    const int* __restrict__ row_ptr, const float* __restrict__ e_meta,
    const unsigned short* __restrict__ phi,
    float* __restrict__ out_v, float* __restrict__ out_s)
{
    __shared__ float meta_lds[2][BATCH * 32];

    const int f = threadIdx.x;               // 0..127 feature lane
    const int gid = blockIdx.x;
    const int chunk = (N_NODES_C + GBLOCKS - 1) / GBLOCKS;
    const int nlo = gid * chunk;
    if (nlo >= N_NODES_C) return;
    const int nhi = min(nlo + chunk, N_NODES_C);

    // per-lane Wr column weights -> registers (fixed by f), once per block
    float wr0[NRBF], wr1[NRBF], wr2[NRBF];
#pragma unroll
    for (int k = 0; k < NRBF; ++k) {
        wr0[k] = Wr[k * 384 +       f];
        wr1[k] = Wr[k * 384 + 128 + f];
        wr2[k] = Wr[k * 384 + 256 + f];
    }
    const float br0 = br[f], br1 = br[128 + f], br2 = br[256 + f];

    const int gbeg = row_ptr[nlo];
    const int gend = row_ptr[nhi];
    const int nedge = gend - gbeg;

    float acc_s = 0.f, acc_v0 = 0.f, acc_v1 = 0.f, acc_v2 = 0.f;

    // leading empty nodes
    int cur = nlo;
    while (cur < nhi && row_ptr[cur + 1] == gbeg) {
        STORE_NODE(cur, 0.f, 0.f, 0.f, 0.f);
        ++cur;
    }
    int end_cur = (cur < nhi) ? row_ptr[cur + 1] : gbeg;

    // stage batch 0
    if (nedge > 0) {
        float4 st0 = ((const float4*)(e_meta + (size_t)gbeg * 32))[threadIdx.x];
        ((float4*)meta_lds[0])[threadIdx.x] = st0;
    }
    __syncthreads();

    const int total_batches = (nedge + BATCH - 1) / BATCH;
    for (int b = 0; b < total_batches; ++b) {
        const int bstart = b * BATCH;
        const int bcount = min(BATCH, nedge - bstart);
        const bool have_next = (b + 1 < total_batches);

        float4 st;
        if (have_next)
            st = ((const float4*)(e_meta + (size_t)(gbeg + bstart + BATCH) * 32))[threadIdx.x];

        const float* M = meta_lds[b & 1];

        float pA0, pA1, pA2, vA0, vA1, vA2;
        float pB0, pB1, pB2, vB0, vB1, vB2;
        {
            int si = __float_as_int(M[24]);
            LOADROWS(pA0, pA1, pA2, vA0, vA1, vA2, si);
        }

        int t = 0;
        while (t < bcount) {
            if (t + 1 < bcount) {
                int si = __float_as_int(M[(t + 1) * 32 + 24]);
                LOADROWS(pB0, pB1, pB2, vB0, vB1, vB2, si);
            }
            COMPUTE(M + t * 32, pA0, pA1, pA2, vA0, vA1, vA2);
            BOUNDARY(gbeg + bstart + t);
            ++t; if (t >= bcount) break;

            if (t + 1 < bcount) {
                int si = __float_as_int(M[(t + 1) * 32 + 24]);
                LOADROWS(pA0, pA1, pA2, vA0, vA1, vA2, si);
            }
            COMPUTE(M + t * 32, pB0, pB1, pB2, vB0, vB1, vB2);
            BOUNDARY(gbeg + bstart + t);
            ++t;
        }

        if (have_next) ((float4*)meta_lds[(b + 1) & 1])[threadIdx.x] = st;
        __syncthreads();
    }
}

// ---------------------------------------------------------------------------
extern "C" void kernel_launch(void* const* d_in, const int* in_sizes, int n_in,
                              void* d_out, int out_size, void* d_ws, size_t ws_size,
                              hipStream_t stream)
{
    const float* s  = (const float*)d_in[0];
    const float* v  = (const float*)d_in[1];
    const float* rp = (const float*)d_in[2];
    const float* W1 = (const float*)d_in[3];
    const float* b1 = (const float*)d_in[4];
    const float* W2 = (const float*)d_in[5];
    const float* b2 = (const float*)d_in[6];
    const float* Wr = (const float*)d_in[7];
    const float* br = (const float*)d_in[8];
    const int* src  = (const int*)d_in[9];
    const int* dst  = (const int*)d_in[10];

    float* out   = (float*)d_out;
    float* out_v = out;                                    // 50000*3*128
    float* out_s = out + (size_t)N_NODES_C * 3 * FDIM;     // 50000*128

    // workspace layout (16B-aligned pieces first); vt LAST so the base
    // layout is identical to the known-good round-7 footprint.
    char* ws0 = (char*)d_ws;
    char* ws  = ws0;
    unsigned short* phi = (unsigned short*)ws;  ws += (size_t)N_NODES_C * 384 * sizeof(unsigned short);
    unsigned short* h   = (unsigned short*)ws;  ws += (size_t)N_NODES_C * 128 * sizeof(unsigned short);
    float* e_meta = (float*)ws;                 ws += ((size_t)N_EDGES_C * 32 + 512) * sizeof(float);
    unsigned short* W1t = (unsigned short*)ws;  ws += (size_t)128 * 128 * sizeof(unsigned short);
    unsigned short* W2t = (unsigned short*)ws;  ws += (size_t)384 * 128 * sizeof(unsigned short);
    int* counts   = (int*)ws;                   ws += (size_t)N_NODES_C * sizeof(int);
    int* row_ptr  = (int*)ws;                   ws += (size_t)(N_NODES_C + 4) * sizeof(int);
    int* row_fill = (int*)ws;                   ws += (size_t)N_NODES_C * sizeof(int);
    int* row_tmp  = (int*)ws;                   ws += (size_t)N_NODES_C * sizeof(int);
    int* partial  = (int*)ws;                   ws += (size_t)256 * sizeof(int);
    int* poffs    = (int*)ws;                   ws += (size_t)256 * sizeof(int);
    unsigned short* vt = (unsigned short*)ws;   ws += (size_t)N_NODES_C * 384 * sizeof(unsigned short);
    const bool use_vt = ((size_t)(ws - ws0) <= ws_size);

    hipMemsetAsync(counts, 0, (size_t)N_NODES_C * sizeof(int), stream);

    count_kernel<<<(N_EDGES_C + 255) / 256, 256, 0, stream>>>(dst, counts);
    scan1_kernel<<<SC_BLK, 256, 0, stream>>>(counts, row_tmp, partial);
    scan2_kernel<<<1, 256, 0, stream>>>(partial, poffs);
    scan3_kernel<<<SC_BLK, 256, 0, stream>>>(row_tmp, poffs, row_ptr, row_fill);
    fill_kernel<<<(N_EDGES_C + 255) / 256, 256, 0, stream>>>(rp, src, dst, row_fill, e_meta);

    prep_w_kernel<<<256, 256, 0, stream>>>(W1, W2, W1t, W2t);
    if (use_vt) vprep_kernel<<<2048, 256, 0, stream>>>(v, vt);
    mlp1_kernel<<<(N_NODES_C + 63) / 64, 256, 0, stream>>>(s, W1t, b1, h);
    mlp2_kernel<<<(N_NODES_C + 63) / 64, 256, 0, stream>>>(h, W2t, b2, phi);

    if (use_vt)
        gather_kernel<true><<<GBLOCKS, 128, 0, stream>>>(v, vt, Wr, br, row_ptr,
                                                         e_meta, phi, out_v, out_s);
    else
        gather_kernel<false><<<GBLOCKS, 128, 0, stream>>>(v, vt, Wr, br, row_ptr,
                                                          e_meta, phi, out_v, out_s);
}

// Round 9
// 286.275 us; speedup vs baseline: 2.1124x; 1.0053x over previous
//
#include <hip/hip_runtime.h>
#include <math.h>

#define N_NODES_C 50000
#define N_EDGES_C 200000
#define FDIM 128
#define NRBF 20
#define CUT 5.0f
#define SC_BLK 196   // ceil(50000/256)
#define GBLOCKS 4096
#define BATCH 16     // edges staged per LDS batch in gather
#define PBLK 4096

typedef short  bf16x8 __attribute__((ext_vector_type(8)));
typedef float  f32x4  __attribute__((ext_vector_type(4)));
typedef unsigned short u16x8 __attribute__((ext_vector_type(8)));

__device__ __forceinline__ unsigned short f32_to_bf16(float f) {
    unsigned u = __float_as_uint(f);
    unsigned r = (u + 0x7FFFu + ((u >> 16) & 1u)) >> 16;   // RNE
    return (unsigned short)r;
}
__device__ __forceinline__ float bf16_to_f32(unsigned short h) {
    return __uint_as_float(((unsigned)h) << 16);
}
__device__ __forceinline__ bf16x8 pack_bf16x8(float4 a, float4 b) {
    bf16x8 r;
    r[0] = (short)f32_to_bf16(a.x); r[1] = (short)f32_to_bf16(a.y);
    r[2] = (short)f32_to_bf16(a.z); r[3] = (short)f32_to_bf16(a.w);
    r[4] = (short)f32_to_bf16(b.x); r[5] = (short)f32_to_bf16(b.y);
    r[6] = (short)f32_to_bf16(b.z); r[7] = (short)f32_to_bf16(b.w);
    return r;
}

// ---------------------------------------------------------------------------
// Weight prep: W1t[n][k] = bf16(W1[k][n]) (128x128), W2t[n][k] = bf16(W2[k][n])
// ---------------------------------------------------------------------------
__global__ __launch_bounds__(256) void prep_w_kernel(
    const float* __restrict__ W1, const float* __restrict__ W2,
    unsigned short* __restrict__ W1t, unsigned short* __restrict__ W2t)
{
    int i = blockIdx.x * 256 + threadIdx.x;
    if (i < 128 * 128) {
        int n = i >> 7, k = i & 127;
        W1t[i] = f32_to_bf16(W1[k * 128 + n]);
    }
    int j = i - 128 * 128;
    if (j >= 0 && j < 384 * 128) {
        int n = j >> 7, k = j & 127;
        W2t[j] = f32_to_bf16(W2[k * 384 + n]);
    }
}

// ---------------------------------------------------------------------------
// Fused MLP (MFMA): PHI = silu(S@W1+b1)@W2 + b2, h staged in LDS.
// 64 rows/block, 4 waves x 16 rows. LDS row padded to 136 ushorts (272B)
// to break the 256B-stride bank collision on stage-2 ds_read_b128.
// ---------------------------------------------------------------------------
__global__ __launch_bounds__(256) void mlp12_kernel(
    const float* __restrict__ s, const unsigned short* __restrict__ W1t,
    const float* __restrict__ b1, const unsigned short* __restrict__ W2t,
    const float* __restrict__ b2, unsigned short* __restrict__ phi)
{
    __shared__ unsigned short hsm[64][136];

    const int wv = threadIdx.x >> 6, lane = threadIdx.x & 63;
    const int m0 = blockIdx.x * 64 + wv * 16;
    const int lr = lane & 15, lg = lane >> 4;
    int arow = m0 + lr; if (arow >= N_NODES_C) arow = N_NODES_C - 1;

    // ---- stage 1: h = silu(s @ W1 + b1) ----
    f32x4 acc[8];
#pragma unroll
    for (int nt = 0; nt < 8; ++nt) acc[nt] = (f32x4){0.f, 0.f, 0.f, 0.f};

#pragma unroll
    for (int kt = 0; kt < 4; ++kt) {
        const int k0 = kt * 32 + lg * 8;
        const float4* ap = (const float4*)(s + (size_t)arow * 128 + k0);
        bf16x8 af = pack_bf16x8(ap[0], ap[1]);
#pragma unroll
        for (int nt = 0; nt < 8; ++nt) {
            bf16x8 bf = *(const bf16x8*)(W1t + (size_t)(nt * 16 + lr) * 128 + k0);
            acc[nt] = __builtin_amdgcn_mfma_f32_16x16x32_bf16(af, bf, acc[nt], 0, 0, 0);
        }
    }

    const int lrow0 = wv * 16 + lg * 4;
#pragma unroll
    for (int nt = 0; nt < 8; ++nt) {
        int col = nt * 16 + lr;
        float bb = b1[col];
#pragma unroll
        for (int r = 0; r < 4; ++r) {
            float x = acc[nt][r] + bb;
            x = x / (1.f + __expf(-x));
            hsm[lrow0 + r][col] = f32_to_bf16(x);
        }
    }
    __syncthreads();

    // ---- stage 2: phi = h @ W2 + b2 ----
    bf16x8 af2[4];
#pragma unroll
    for (int kt = 0; kt < 4; ++kt)
        af2[kt] = *(const bf16x8*)&hsm[wv * 16 + lr][kt * 32 + lg * 8];

    const int crow = m0 + lg * 4;
#pragma unroll
    for (int c = 0; c < 3; ++c) {
        const int nbase = c * 128;
        f32x4 acc2[8];
#pragma unroll
        for (int nt = 0; nt < 8; ++nt) acc2[nt] = (f32x4){0.f, 0.f, 0.f, 0.f};

#pragma unroll
        for (int kt = 0; kt < 4; ++kt) {
            const int k0 = kt * 32 + lg * 8;
#pragma unroll
            for (int nt = 0; nt < 8; ++nt) {
                bf16x8 bf = *(const bf16x8*)(W2t + (size_t)(nbase + nt * 16 + lr) * 128 + k0);
                acc2[nt] = __builtin_amdgcn_mfma_f32_16x16x32_bf16(af2[kt], bf, acc2[nt], 0, 0, 0);
            }
        }

#pragma unroll
        for (int nt = 0; nt < 8; ++nt) {
            int col = nt * 16 + lr;
            float bb = b2[nbase + col];
#pragma unroll
            for (int r = 0; r < 4; ++r) {
                int m = crow + r;
                if (m < N_NODES_C)
                    phi[(size_t)m * 384 + nbase + col] = f32_to_bf16(acc2[nt][r] + bb);
            }
        }
    }
}

// ---------------------------------------------------------------------------
// Pack: pv[n][f][8] = {phi0, phi1, phi2, v0, v1, v2, 0, 0} (bf16), 16B/feature.
// One fully-coalesced ushort8 row per node; gather does ONE dwordx4 per edge.
// Block = 128 threads = 2 nodes x 64 feature-pairs.
// ---------------------------------------------------------------------------
__global__ __launch_bounds__(128) void pack_kernel(
    const unsigned short* __restrict__ phi, const float* __restrict__ v,
    unsigned short* __restrict__ pv)
{
    const int sub = threadIdx.x >> 6;      // node within pair
    const int f2  = threadIdx.x & 63;      // feature pair 0..63
    for (int np = blockIdx.x; np < N_NODES_C / 2; np += gridDim.x) {
        const int n = np * 2 + sub;
        const ushort2* p  = (const ushort2*)(phi + (size_t)n * 384);
        const float2*  vv = (const float2*)(v   + (size_t)n * 384);
        ushort2 a0 = p[f2], a1 = p[64 + f2], a2 = p[128 + f2];
        float2  c0 = vv[f2], c1 = vv[64 + f2], c2 = vv[128 + f2];
        u16x8 o0, o1;
        o0[0] = a0.x; o0[1] = a1.x; o0[2] = a2.x;
        o0[3] = f32_to_bf16(c0.x); o0[4] = f32_to_bf16(c1.x); o0[5] = f32_to_bf16(c2.x);
        o0[6] = 0; o0[7] = 0;
        o1[0] = a0.y; o1[1] = a1.y; o1[2] = a2.y;
        o1[3] = f32_to_bf16(c0.y); o1[4] = f32_to_bf16(c1.y); o1[5] = f32_to_bf16(c2.y);
        o1[6] = 0; o1[7] = 0;
        u16x8* outp = (u16x8*)(pv + (size_t)n * 1024 + (size_t)f2 * 16);
        outp[0] = o0;
        outp[1] = o1;
    }
}

// ---------------------------------------------------------------------------
// v -> bf16 copy (fallback path only)
// ---------------------------------------------------------------------------
__global__ __launch_bounds__(256) void vprep_kernel(
    const float* __restrict__ v, unsigned short* __restrict__ vt)
{
    const size_t total = (size_t)N_NODES_C * 96;   // float4 count (384/4)
    for (size_t i = (size_t)blockIdx.x * 256 + threadIdx.x; i < total;
         i += (size_t)gridDim.x * 256) {
        float4 a = ((const float4*)v)[i];
        ushort4 o;
        o.x = f32_to_bf16(a.x); o.y = f32_to_bf16(a.y);
        o.z = f32_to_bf16(a.z); o.w = f32_to_bf16(a.w);
        ((ushort4*)vt)[i] = o;
    }
}

// ---------------------------------------------------------------------------
// CSR build: histogram -> 3-kernel parallel scan -> fill
// ---------------------------------------------------------------------------
__global__ __launch_bounds__(256) void count_kernel(
    const int* __restrict__ dst, int* __restrict__ counts)
{
    int e = blockIdx.x * 256 + threadIdx.x;
    if (e < N_EDGES_C) atomicAdd(counts + dst[e], 1);
}

__global__ __launch_bounds__(256) void scan1_kernel(
    const int* __restrict__ counts, int* __restrict__ row_tmp,
    int* __restrict__ partial)
{
    __shared__ int sm[256];
    const int t = threadIdx.x;
    const int idx = blockIdx.x * 256 + t;
    int c = (idx < N_NODES_C) ? counts[idx] : 0;
    int x = c;
    sm[t] = x;
    __syncthreads();
#pragma unroll
    for (int off = 1; off < 256; off <<= 1) {
        int y = (t >= off) ? sm[t - off] : 0;
        __syncthreads();
        x += y;
        sm[t] = x;
        __syncthreads();
    }
    if (idx < N_NODES_C) row_tmp[idx] = x - c;
    if (t == 255) partial[blockIdx.x] = x;
}

__global__ __launch_bounds__(256) void scan2_kernel(
    const int* __restrict__ partial, int* __restrict__ poffs)
{
    __shared__ int sm[256];
    const int t = threadIdx.x;
    int c = (t < SC_BLK) ? partial[t] : 0;
    int x = c;
    sm[t] = x;
    __syncthreads();
#pragma unroll
    for (int off = 1; off < 256; off <<= 1) {
        int y = (t >= off) ? sm[t - off] : 0;
        __syncthreads();
        x += y;
        sm[t] = x;
        __syncthreads();
    }
    if (t < SC_BLK) poffs[t] = x - c;
}

__global__ __launch_bounds__(256) void scan3_kernel(
    const int* __restrict__ row_tmp, const int* __restrict__ poffs,
    int* __restrict__ row_ptr, int* __restrict__ row_fill)
{
    const int idx = blockIdx.x * 256 + threadIdx.x;
    if (idx < N_NODES_C) {
        int rp = row_tmp[idx] + poffs[blockIdx.x];
        row_ptr[idx]  = rp;
        row_fill[idx] = rp;
    }
    if (idx == 0) row_ptr[N_NODES_C] = N_EDGES_C;
}

// ---------------------------------------------------------------------------
// Edge precompute into dst-sorted slots; 128B (32-float) blob per edge:
//   [0..2]=dir, [3]=fcut, [4..23]=rbf[k]*invd*fcut, [24]=bitcast(src), rest pad
// ---------------------------------------------------------------------------
__global__ __launch_bounds__(256) void fill_kernel(
    const float* __restrict__ rel_pos, const int* __restrict__ src,
    const int* __restrict__ dst, int* __restrict__ row_fill,
    float* __restrict__ e_meta)
{
    int e = blockIdx.x * 256 + threadIdx.x;
    if (e >= N_EDGES_C) return;

    int pos = atomicAdd(row_fill + dst[e], 1);

    float x = rel_pos[3 * e + 0];
    float y = rel_pos[3 * e + 1];
    float z = rel_pos[3 * e + 2];
    float d = sqrtf(x * x + y * y + z * z);
    float invd = 1.0f / d;

    float s1 = 0.f, c1 = 0.f, fcut = 0.f, amp = 0.f;
    if (d < CUT) {
        sincosf((3.14159265358979f / CUT) * d, &s1, &c1);
        fcut = 0.5f * (c1 + 1.0f);
        amp  = invd * fcut;
    }

    float rb[NRBF];
    float sk = s1, ck = c1;
#pragma unroll
    for (int k = 0; k < NRBF; ++k) {
        rb[k] = sk * amp;
        float sn = sk * c1 + ck * s1;
        ck = ck * c1 - sk * s1;
        sk = sn;
    }

    float4* mp = (float4*)(e_meta + (size_t)pos * 32);
    mp[0] = make_float4(x * invd, y * invd, z * invd, fcut);
    mp[1] = make_float4(rb[0],  rb[1],  rb[2],  rb[3]);
    mp[2] = make_float4(rb[4],  rb[5],  rb[6],  rb[7]);
    mp[3] = make_float4(rb[8],  rb[9],  rb[10], rb[11]);
    mp[4] = make_float4(rb[12], rb[13], rb[14], rb[15]);
    mp[5] = make_float4(rb[16], rb[17], rb[18], rb[19]);
    mp[6] = make_float4(__int_as_float(src[e]), 0.f, 0.f, 0.f);
}

// ---------------------------------------------------------------------------
// Gather common pieces
// NOTE: no min-waves launch_bounds clause (round-5 spill lesson).
// ---------------------------------------------------------------------------
#define DOT_AND_ACC(MP, P0, P1, P2, V0, V1, V2)                                \
    {                                                                          \
        const float* mp_ = (MP);                                               \
        float4 m0 = *(const float4*)(mp_);                                     \
        float4 m1 = *(const float4*)(mp_ + 4);                                 \
        float4 m2 = *(const float4*)(mp_ + 8);                                 \
        float4 m3 = *(const float4*)(mp_ + 12);                                \
        float4 m4 = *(const float4*)(mp_ + 16);                                \
        float4 m5 = *(const float4*)(mp_ + 20);                                \
        float rr[NRBF] = {m1.x, m1.y, m1.z, m1.w, m2.x, m2.y, m2.z, m2.w,      \
                          m3.x, m3.y, m3.z, m3.w, m4.x, m4.y, m4.z, m4.w,      \
                          m5.x, m5.y, m5.z, m5.w};                             \
        float w0 = br0 * m0.w, w1 = br1 * m0.w, w2 = br2 * m0.w;               \
        _Pragma("unroll")                                                      \
        for (int k = 0; k < NRBF; ++k) {                                       \
            w0 += rr[k] * wr0[k];                                              \
            w1 += rr[k] * wr1[k];                                              \
            w2 += rr[k] * wr2[k];                                              \
        }                                                                      \
        float sv = w0 * (P0);                                                  \
        float ss = w1 * (P1);                                                  \
        float sr = w2 * (P2);                                                  \
        acc_s  += ss;                                                          \
        acc_v0 += (V0) * sv + m0.x * sr;                                       \
        acc_v1 += (V1) * sv + m0.y * sr;                                       \
        acc_v2 += (V2) * sv + m0.z * sr;                                       \
    }

#define COMPUTEP(MP, U)                                                        \
    {                                                                          \
        float P0_ = bf16_to_f32((unsigned short)(U)[0]);                       \
        float P1_ = bf16_to_f32((unsigned short)(U)[1]);                       \
        float P2_ = bf16_to_f32((unsigned short)(U)[2]);                       \
        float V0_ = bf16_to_f32((unsigned short)(U)[3]);                       \
        float V1_ = bf16_to_f32((unsigned short)(U)[4]);                       \
        float V2_ = bf16_to_f32((unsigned short)(U)[5]);                       \
        DOT_AND_ACC(MP, P0_, P1_, P2_, V0_, V1_, V2_)                          \
    }

#define STORE_NODE(N_, AS, A0, A1, A2)                                         \
    {                                                                          \
        out_s[(size_t)(N_) * 128 + f] = AS;                                    \
        out_v[(size_t)(N_) * 384 +       f] = A0;                              \
        out_v[(size_t)(N_) * 384 + 128 + f] = A1;                              \
        out_v[(size_t)(N_) * 384 + 256 + f] = A2;                              \
    }

#define BOUNDARY(GE)                                                           \
    if ((GE) + 1 == end_cur) {                                                 \
        STORE_NODE(cur, acc_s, acc_v0, acc_v1, acc_v2);                        \
        acc_s = acc_v0 = acc_v1 = acc_v2 = 0.f;                                \
        ++cur;                                                                 \
        while (cur < nhi) {                                                    \
            int ne_ = row_ptr[cur + 1];                                        \
            if (ne_ != (GE) + 1) { end_cur = ne_; break; }                     \
            STORE_NODE(cur, 0.f, 0.f, 0.f, 0.f);                               \
            ++cur;                                                             \
        }                                                                      \
    }

// ---------------------------------------------------------------------------
// Packed gather: ONE dwordx4 gather per edge per lane from pv.
// ---------------------------------------------------------------------------
__global__ __launch_bounds__(128) void gather_packed_kernel(
    const unsigned short* __restrict__ pv, const float* __restrict__ Wr,
    const float* __restrict__ br, const int* __restrict__ row_ptr,
    const float* __restrict__ e_meta,
    float* __restrict__ out_v, float* __restrict__ out_s)
{
    __shared__ float meta_lds[2][BATCH * 32];

    const int f = threadIdx.x;               // 0..127 feature lane
    const int gid = blockIdx.x;
    const int chunk = (N_NODES_C + GBLOCKS - 1) / GBLOCKS;
    const int nlo = gid * chunk;
    if (nlo >= N_NODES_C) return;
    const int nhi = min(nlo + chunk, N_NODES_C);

    float wr0[NRBF], wr1[NRBF], wr2[NRBF];
#pragma unroll
    for (int k = 0; k < NRBF; ++k) {
        wr0[k] = Wr[k * 384 +       f];
        wr1[k] = Wr[k * 384 + 128 + f];
        wr2[k] = Wr[k * 384 + 256 + f];
    }
    const float br0 = br[f], br1 = br[128 + f], br2 = br[256 + f];

    const int gbeg = row_ptr[nlo];
    const int gend = row_ptr[nhi];
    const int nedge = gend - gbeg;

    float acc_s = 0.f, acc_v0 = 0.f, acc_v1 = 0.f, acc_v2 = 0.f;

    int cur = nlo;
    while (cur < nhi && row_ptr[cur + 1] == gbeg) {
        STORE_NODE(cur, 0.f, 0.f, 0.f, 0.f);
        ++cur;
    }
    int end_cur = (cur < nhi) ? row_ptr[cur + 1] : gbeg;

    if (nedge > 0) {
        float4 st0 = ((const float4*)(e_meta + (size_t)gbeg * 32))[threadIdx.x];
        ((float4*)meta_lds[0])[threadIdx.x] = st0;
    }
    __syncthreads();

    const int total_batches = (nedge + BATCH - 1) / BATCH;
    for (int b = 0; b < total_batches; ++b) {
        const int bstart = b * BATCH;
        const int bcount = min(BATCH, nedge - bstart);
        const bool have_next = (b + 1 < total_batches);

        float4 st;
        if (have_next)
            st = ((const float4*)(e_meta + (size_t)(gbeg + bstart + BATCH) * 32))[threadIdx.x];

        const float* M = meta_lds[b & 1];

        u16x8 uA, uB;
        {
            int si = __float_as_int(M[24]);
            uA = *(const u16x8*)(pv + (size_t)si * 1024 + (size_t)f * 8);
        }

        int t = 0;
        while (t < bcount) {
            if (t + 1 < bcount) {
                int si = __float_as_int(M[(t + 1) * 32 + 24]);
                uB = *(const u16x8*)(pv + (size_t)si * 1024 + (size_t)f * 8);
            }
            COMPUTEP(M + t * 32, uA);
            BOUNDARY(gbeg + bstart + t);
            ++t; if (t >= bcount) break;

            if (t + 1 < bcount) {
                int si = __float_as_int(M[(t + 1) * 32 + 24]);
                uA = *(const u16x8*)(pv + (size_t)si * 1024 + (size_t)f * 8);
            }
            COMPUTEP(M + t * 32, uB);
            BOUNDARY(gbeg + bstart + t);
            ++t;
        }

        if (have_next) ((float4*)meta_lds[(b + 1) & 1])[threadIdx.x] = st;
        __syncthreads();
    }
}

// ---------------------------------------------------------------------------
// Legacy gather (fallback when pv doesn't fit d_ws): round-8 structure,
// 6 scalar bf16 gathers per edge from phi + vt.
// ---------------------------------------------------------------------------
#define LOADROWS_L(P0, P1, P2, V0, V1, V2, SI)                                 \
    {                                                                          \
        const unsigned short* ph_ = phi + (size_t)(SI) * 384;                  \
        const unsigned short* vr_ = vt  + (size_t)(SI) * 384;                  \
        P0 = bf16_to_f32(ph_[f]);                                              \
        P1 = bf16_to_f32(ph_[128 + f]);                                        \
        P2 = bf16_to_f32(ph_[256 + f]);                                        \
        V0 = bf16_to_f32(vr_[f]);                                              \
        V1 = bf16_to_f32(vr_[128 + f]);                                        \
        V2 = bf16_to_f32(vr_[256 + f]);                                        \
    }

__global__ __launch_bounds__(128) void gather_legacy_kernel(
    const unsigned short* __restrict__ vt, const float* __restrict__ Wr,
    const float* __restrict__ br, const int* __restrict__ row_ptr,
    const float* __restrict__ e_meta, const unsigned short* __restrict__ phi,
    float* __restrict__ out_v, float* __restrict__ out_s)
{
    __shared__ float meta_lds[2][BATCH * 32];

    const int f = threadIdx.x;
    const int gid = blockIdx.x;
    const int chunk = (N_NODES_C + GBLOCKS - 1) / GBLOCKS;
    const int nlo = gid * chunk;
    if (nlo >= N_NODES_C) return;
    const int nhi = min(nlo + chunk, N_NODES_C);

    float wr0[NRBF], wr1[NRBF], wr2[NRBF];
#pragma unroll
    for (int k = 0; k < NRBF; ++k) {
        wr0[k] = Wr[k * 384 +       f];
        wr1[k] = Wr[k * 384 + 128 + f];
        wr2[k] = Wr[k * 384 + 256 + f];
    }
    const float br0 = br[f], br1 = br[128 + f], br2 = br[256 + f];

    const int gbeg = row_ptr[nlo];
    const int gend = row_ptr[nhi];
    const int nedge = gend - gbeg;

    float acc_s = 0.f, acc_v0 = 0.f, acc_v1 = 0.f, acc_v2 = 0.f;

    int cur = nlo;
    while (cur < nhi && row_ptr[cur + 1] == gbeg) {
        STORE_NODE(cur, 0.f, 0.f, 0.f, 0.f);
        ++cur;
    }
    int end_cur = (cur < nhi) ? row_ptr[cur + 1] : gbeg;

    if (nedge > 0) {
        float4 st0 = ((const float4*)(e_meta + (size_t)gbeg * 32))[threadIdx.x];
        ((float4*)meta_lds[0])[threadIdx.x] = st0;
    }
    __syncthreads();

    const int total_batches = (nedge + BATCH - 1) / BATCH;
    for (int b = 0; b < total_batches; ++b) {
        const int bstart = b * BATCH;
        const int bcount = min(BATCH, nedge - bstart);
        const bool have_next = (b + 1 < total_batches);

        float4 st;
        if (have_next)
            st = ((const float4*)(e_meta + (size_t)(gbeg + bstart + BATCH) * 32))[threadIdx.x];

        const float* M = meta_lds[b & 1];

        float pA0, pA1, pA2, vA0, vA1, vA2;
        float pB0, pB1, pB2, vB0, vB1, vB2;
        {
            int si = __float_as_int(M[24]);
            LOADROWS_L(pA0, pA1, pA2, vA0, vA1, vA2, si);
        }

        int t = 0;
        while (t < bcount) {
            if (t + 1 < bcount) {
                int si = __float_as_int(M[(t + 1) * 32 + 24]);
                LOADROWS_L(pB0, pB1, pB2, vB0, vB1, vB2, si);
            }
            DOT_AND_ACC(M + t * 32, pA0, pA1, pA2, vA0, vA1, vA2);
            BOUNDARY(gbeg + bstart + t);
            ++t; if (t >= bcount) break;

            if (t + 1 < bcount) {
                int si = __float_as_int(M[(t + 1) * 32 + 24]);
                LOADROWS_L(pA0, pA1, pA2, vA0, vA1, vA2, si);
            }
            DOT_AND_ACC(M + t * 32, pB0, pB1, pB2, vB0, vB1, vB2);
            BOUNDARY(gbeg + bstart + t);
            ++t;
        }

        if (have_next) ((float4*)meta_lds[(b + 1) & 1])[threadIdx.x] = st;
        __syncthreads();
    }
}

// ---------------------------------------------------------------------------
extern "C" void kernel_launch(void* const* d_in, const int* in_sizes, int n_in,
                              void* d_out, int out_size, void* d_ws, size_t ws_size,
                              hipStream_t stream)
{
    const float* s  = (const float*)d_in[0];
    const float* v  = (const float*)d_in[1];
    const float* rp = (const float*)d_in[2];
    const float* W1 = (const float*)d_in[3];
    const float* b1 = (const float*)d_in[4];
    const float* W2 = (const float*)d_in[5];
    const float* b2 = (const float*)d_in[6];
    const float* Wr = (const float*)d_in[7];
    const float* br = (const float*)d_in[8];
    const int* src  = (const int*)d_in[9];
    const int* dst  = (const int*)d_in[10];

    float* out   = (float*)d_out;
    float* out_v = out;                                    // 50000*3*128
    float* out_s = out + (size_t)N_NODES_C * 3 * FDIM;     // 50000*128

    // workspace layout; BIG (pv or vt) region last.
    char* ws0 = (char*)d_ws;
    char* ws  = ws0;
    unsigned short* phi = (unsigned short*)ws;  ws += (size_t)N_NODES_C * 384 * sizeof(unsigned short);
    float* e_meta = (float*)ws;                 ws += ((size_t)N_EDGES_C * 32 + 512) * sizeof(float);
    unsigned short* W1t = (unsigned short*)ws;  ws += (size_t)128 * 128 * sizeof(unsigned short);
    unsigned short* W2t = (unsigned short*)ws;  ws += (size_t)384 * 128 * sizeof(unsigned short);
    int* counts   = (int*)ws;                   ws += (size_t)N_NODES_C * sizeof(int);
    int* row_ptr  = (int*)ws;                   ws += (size_t)(N_NODES_C + 4) * sizeof(int);
    int* row_fill = (int*)ws;                   ws += (size_t)N_NODES_C * sizeof(int);
    int* row_tmp  = (int*)ws;                   ws += (size_t)N_NODES_C * sizeof(int);
    int* partial  = (int*)ws;                   ws += (size_t)256 * sizeof(int);
    int* poffs    = (int*)ws;                   ws += (size_t)256 * sizeof(int);
    unsigned short* big = (unsigned short*)ws;  // pv (102.4MB) or vt (38.4MB)
    const size_t base = (size_t)(ws - ws0);
    const bool use_packed = base + (size_t)N_NODES_C * 1024 * sizeof(unsigned short) <= ws_size;

    hipMemsetAsync(counts, 0, (size_t)N_NODES_C * sizeof(int), stream);

    count_kernel<<<(N_EDGES_C + 255) / 256, 256, 0, stream>>>(dst, counts);
    scan1_kernel<<<SC_BLK, 256, 0, stream>>>(counts, row_tmp, partial);
    scan2_kernel<<<1, 256, 0, stream>>>(partial, poffs);
    scan3_kernel<<<SC_BLK, 256, 0, stream>>>(row_tmp, poffs, row_ptr, row_fill);
    fill_kernel<<<(N_EDGES_C + 255) / 256, 256, 0, stream>>>(rp, src, dst, row_fill, e_meta);

    prep_w_kernel<<<256, 256, 0, stream>>>(W1, W2, W1t, W2t);
    mlp12_kernel<<<(N_NODES_C + 63) / 64, 256, 0, stream>>>(s, W1t, b1, W2t, b2, phi);

    if (use_packed) {
        pack_kernel<<<PBLK, 128, 0, stream>>>(phi, v, big);
        gather_packed_kernel<<<GBLOCKS, 128, 0, stream>>>(big, Wr, br, row_ptr,
                                                          e_meta, out_v, out_s);
    } else {
        vprep_kernel<<<2048, 256, 0, stream>>>(v, big);
        gather_legacy_kernel<<<GBLOCKS, 128, 0, stream>>>(big, Wr, br, row_ptr,
                                                          e_meta, phi, out_v, out_s);
    }
}